// Round 2
// baseline (7932.575 us; speedup 1.0000x reference)
//
#include <hip/hip_runtime.h>
#include <math.h>
#include <stdint.h>
#include <stddef.h>

#define HID 2048
#define NH 16
#define NKV 4
#define HD 128
#define GROUPS (NH / NKV)
#define BATCH 2
#define SEQ 2048

// clip(round(x/s), -128, 127) -> integer-valued float
__device__ inline float quantv(float x, float s) {
  float q = rintf(x / s);
  return fminf(fmaxf(q, -128.0f), 127.0f);
}

__device__ inline float slot_scale(const unsigned int* slots, int i) {
  return fmaxf(__uint_as_float(slots[i]) / 127.0f, 1e-8f);
}

// ---------------- absmax reduction ----------------
__global__ __launch_bounds__(256) void absmax_k(const float* __restrict__ x, size_t n,
                                                unsigned int* __restrict__ slot) {
  float m = 0.0f;
  for (size_t i = (size_t)blockIdx.x * 256 + threadIdx.x; i < n; i += (size_t)gridDim.x * 256)
    m = fmaxf(m, fabsf(x[i]));
  __shared__ float red[256];
  red[threadIdx.x] = m;
  __syncthreads();
  for (int o = 128; o > 0; o >>= 1) {
    if (threadIdx.x < o) red[threadIdx.x] = fmaxf(red[threadIdx.x], red[threadIdx.x + o]);
    __syncthreads();
  }
  if (threadIdx.x == 0) atomicMax(slot, __float_as_uint(red[0]));
}

// ---------------- quantize-on-load GEMM: C[m,n] = sa*sb * sum_k q(A[m,k])*q(B[n,k]) ----
// A: [M,K], B: [N,K] (row-major), C: [M,N] fp32
__global__ __launch_bounds__(256) void gemm_quant(const float* __restrict__ A,
                                                  const float* __restrict__ Bw,
                                                  float* __restrict__ C, int M, int N, int K,
                                                  const unsigned int* __restrict__ slots,
                                                  int ia, int ib) {
  __shared__ float As[16][65];
  __shared__ float Bs[16][65];
  const float sa = slot_scale(slots, ia);
  const float sb = slot_scale(slots, ib);
  const int tid = threadIdx.x;
  const int tx = tid & 15, ty = tid >> 4;
  const int n0 = blockIdx.x * 64, m0 = blockIdx.y * 64;
  const int lr = tid >> 2;         // 0..63
  const int lc = (tid & 3) * 4;    // 0,4,8,12
  float acc[4][4] = {{0.f}};
  for (int kt = 0; kt < K; kt += 16) {
    const float* ap = A + (size_t)(m0 + lr) * K + kt + lc;
    const float* bp = Bw + (size_t)(n0 + lr) * K + kt + lc;
#pragma unroll
    for (int i = 0; i < 4; i++) As[lc + i][lr] = quantv(ap[i], sa);
#pragma unroll
    for (int i = 0; i < 4; i++) Bs[lc + i][lr] = quantv(bp[i], sb);
    __syncthreads();
#pragma unroll
    for (int k = 0; k < 16; k++) {
      float av[4], bv[4];
#pragma unroll
      for (int i = 0; i < 4; i++) av[i] = As[k][ty * 4 + i];
#pragma unroll
      for (int j = 0; j < 4; j++) bv[j] = Bs[k][tx * 4 + j];
#pragma unroll
      for (int i = 0; i < 4; i++)
#pragma unroll
        for (int j = 0; j < 4; j++) acc[i][j] += av[i] * bv[j];
    }
    __syncthreads();
  }
  const float sc = sa * sb;
#pragma unroll
  for (int i = 0; i < 4; i++)
#pragma unroll
    for (int j = 0; j < 4; j++)
      C[(size_t)(m0 + ty * 4 + i) * N + (n0 + tx * 4 + j)] = acc[i][j] * sc;
}

// ---------------- RoPE in-place + absmax ----------------
__global__ __launch_bounds__(256) void rope_kernel(float* __restrict__ t, int nh,
                                                   unsigned int* __restrict__ slot) {
  size_t idx = (size_t)blockIdx.x * 256 + threadIdx.x;
  size_t total = (size_t)BATCH * SEQ * nh * (HD / 2);
  float am = 0.0f;
  if (idx < total) {
    int i = (int)(idx & 63);
    int h = (int)((idx >> 6) % nh);
    int s = (int)((idx / (64ull * nh)) % SEQ);
    int b = (int)(idx / (64ull * nh * SEQ));
    size_t base = ((size_t)(b * SEQ + s) * nh + h) * HD;
    float inv = 1.0f / powf(10000.0f, (float)(2 * i) * (1.0f / 128.0f));
    float fr = (float)s * inv;
    float c = cosf(fr), sn = sinf(fr);
    float x1 = t[base + i], x2 = t[base + i + 64];
    float r1 = x1 * c - x2 * sn;
    float r2 = x2 * c + x1 * sn;
    t[base + i] = r1;
    t[base + i + 64] = r2;
    am = fmaxf(fabsf(r1), fabsf(r2));
  }
  __shared__ float red[256];
  red[threadIdx.x] = am;
  __syncthreads();
  for (int o = 128; o > 0; o >>= 1) {
    if (threadIdx.x < o) red[threadIdx.x] = fmaxf(red[threadIdx.x], red[threadIdx.x + o]);
    __syncthreads();
  }
  if (threadIdx.x == 0) atomicMax(slot, __float_as_uint(red[0]));
}

// ---------------- in-place per-tensor quantization ----------------
__global__ __launch_bounds__(256) void quant_inplace(float* __restrict__ x, size_t n,
                                                     const unsigned int* __restrict__ slot) {
  float s = fmaxf(__uint_as_float(*slot) / 127.0f, 1e-8f);
  for (size_t i = (size_t)blockIdx.x * 256 + threadIdx.x; i < n; i += (size_t)gridDim.x * 256)
    x[i] = quantv(x[i], s);
}

// ---------------- per-row causal attention ----------------
// q,k,v hold integer-valued floats (already fake-quant'd). Output: raw fp32 attn_output,
// plus fused absmax -> slots[8].
__global__ __launch_bounds__(256) void attn_row_kernel(const float* __restrict__ qb,
                                                       const float* __restrict__ kb,
                                                       const float* __restrict__ vb,
                                                       float* __restrict__ ob,
                                                       unsigned int* __restrict__ slots) {
  __shared__ float scb[SEQ];
  __shared__ float qq[HD];
  __shared__ float red[256];
  const int tid = threadIdx.x;
  const int blk = blockIdx.x;
  const int qpos = blk % SEQ;
  const int h = (blk / SEQ) % NH;
  const int b = blk / (SEQ * NH);
  const int hk = h / GROUPS;
  const float s_q = slot_scale(slots, 5);
  const float s_k = slot_scale(slots, 6);
  const float s_v = slot_scale(slots, 7);
  const int nk = qpos + 1;
  if (tid < HD) qq[tid] = qb[((size_t)(b * SEQ + qpos) * NH + h) * HD + tid];
  __syncthreads();
  const float sscale = s_q * s_k / 11.313708498984761f;  // / sqrt(128)
  float lmax = -INFINITY;
  for (int j = tid; j < nk; j += 256) {
    const float* kr = kb + ((size_t)(b * SEQ + j) * NKV + hk) * HD;
    float acc = 0.0f;
#pragma unroll 8
    for (int d = 0; d < HD; d++) acc += qq[d] * kr[d];
    float v = acc * sscale;
    scb[j] = v;
    lmax = fmaxf(lmax, v);
  }
  red[tid] = lmax;
  __syncthreads();
  for (int o = 128; o > 0; o >>= 1) {
    if (tid < o) red[tid] = fmaxf(red[tid], red[tid + o]);
    __syncthreads();
  }
  const float m = red[0];
  __syncthreads();
  float lsum = 0.0f;
  for (int j = tid; j < nk; j += 256) {
    float e = expf(scb[j] - m);
    scb[j] = e;
    lsum += e;
  }
  red[tid] = lsum;
  __syncthreads();
  for (int o = 128; o > 0; o >>= 1) {
    if (tid < o) red[tid] += red[tid + o];
    __syncthreads();
  }
  const float l = red[0];
  __syncthreads();
  // p fake-quant: global softmax absmax is exactly 1.0 (row 0) -> scale_p = 1/127
  const float scale_p = 1.0f / 127.0f;
  for (int j = tid; j < nk; j += 256) scb[j] = rintf((scb[j] / l) / scale_p);
  __syncthreads();
  const int d = tid & 127, half = tid >> 7;
  float acc = 0.0f;
  for (int j = half; j < nk; j += 2)
    acc += scb[j] * vb[((size_t)(b * SEQ + j) * NKV + hk) * HD + d];
  red[tid] = acc;
  __syncthreads();
  float oval = 0.0f;
  if (tid < HD) {
    oval = (red[tid] + red[tid + HD]) * (scale_p * s_v);
    ob[((size_t)(b * SEQ + qpos) * NH + h) * HD + tid] = oval;
  }
  __syncthreads();
  red[tid] = fabsf(oval);
  __syncthreads();
  for (int o = 128; o > 0; o >>= 1) {
    if (tid < o) red[tid] = fmaxf(red[tid], red[tid + o]);
    __syncthreads();
  }
  if (tid == 0) atomicMax(&slots[8], __float_as_uint(red[0]));
}

extern "C" void kernel_launch(void* const* d_in, const int* in_sizes, int n_in,
                              void* d_out, int out_size, void* d_ws, size_t ws_size,
                              hipStream_t stream) {
  const float* hs = (const float*)d_in[0];
  // d_in[1] attention_mask (standard causal, rebuilt implicitly)
  // d_in[2] position_ids (arange, rebuilt implicitly)
  const float* wq = (const float*)d_in[3];
  const float* wk = (const float*)d_in[4];
  const float* wv = (const float*)d_in[5];
  const float* wo = (const float*)d_in[6];
  float* out = (float*)d_out;

  unsigned int* slots = (unsigned int*)d_ws;
  float* base = (float*)d_ws;
  float* qbuf = base + 64;
  float* kbuf = qbuf + (size_t)BATCH * SEQ * NH * HD;
  float* vbuf = kbuf + (size_t)BATCH * SEQ * NKV * HD;
  float* aobuf = vbuf + (size_t)BATCH * SEQ * NKV * HD;

  hipMemsetAsync(d_ws, 0, 64 * sizeof(float), stream);

  const size_t n_hs = (size_t)BATCH * SEQ * HID;
  const size_t n_wq = (size_t)NH * HD * HID;
  const size_t n_wkv = (size_t)NKV * HD * HID;
  const size_t n_wo = (size_t)HID * NH * HD;
  // slots: 0=x 1=wq 2=wk 3=wv 4=wo 5=q 6=k 7=v 8=ao
  absmax_k<<<1024, 256, 0, stream>>>(hs, n_hs, slots + 0);
  absmax_k<<<512, 256, 0, stream>>>(wq, n_wq, slots + 1);
  absmax_k<<<256, 256, 0, stream>>>(wk, n_wkv, slots + 2);
  absmax_k<<<256, 256, 0, stream>>>(wv, n_wkv, slots + 3);
  absmax_k<<<512, 256, 0, stream>>>(wo, n_wo, slots + 4);

  const int M = BATCH * SEQ;
  gemm_quant<<<dim3((NH * HD) / 64, M / 64), 256, 0, stream>>>(hs, wq, qbuf, M, NH * HD, HID,
                                                               slots, 0, 1);
  gemm_quant<<<dim3((NKV * HD) / 64, M / 64), 256, 0, stream>>>(hs, wk, kbuf, M, NKV * HD, HID,
                                                                slots, 0, 2);
  gemm_quant<<<dim3((NKV * HD) / 64, M / 64), 256, 0, stream>>>(hs, wv, vbuf, M, NKV * HD, HID,
                                                                slots, 0, 3);

  rope_kernel<<<(BATCH * SEQ * NH * (HD / 2)) / 256, 256, 0, stream>>>(qbuf, NH, slots + 5);
  rope_kernel<<<(BATCH * SEQ * NKV * (HD / 2)) / 256, 256, 0, stream>>>(kbuf, NKV, slots + 6);
  absmax_k<<<256, 256, 0, stream>>>(vbuf, (size_t)BATCH * SEQ * NKV * HD, slots + 7);

  quant_inplace<<<1024, 256, 0, stream>>>(qbuf, (size_t)BATCH * SEQ * NH * HD, slots + 5);
  quant_inplace<<<512, 256, 0, stream>>>(kbuf, (size_t)BATCH * SEQ * NKV * HD, slots + 6);
  quant_inplace<<<512, 256, 0, stream>>>(vbuf, (size_t)BATCH * SEQ * NKV * HD, slots + 7);

  attn_row_kernel<<<BATCH * NH * SEQ, 256, 0, stream>>>(qbuf, kbuf, vbuf, aobuf, slots);

  gemm_quant<<<dim3(HID / 64, M / 64), 256, 0, stream>>>(aobuf, wo, out, M, HID, NH * HD,
                                                         slots, 8, 4);
}

// Round 5
// 2795.018 us; speedup vs baseline: 2.8381x; 2.8381x over previous
//
#include <hip/hip_runtime.h>
#include <math.h>
#include <stdint.h>
#include <stddef.h>

#define HID 2048
#define NH 16
#define NKV 4
#define HD 128
#define GROUPS (NH / NKV)
#define BATCH 2
#define SEQ 2048

#define NEG_BIG (-3.0e38f)

typedef __attribute__((ext_vector_type(8))) short bf16x8;
typedef __attribute__((ext_vector_type(4))) float f32x4;

// clip(round(x/s), -128, 127) -> integer-valued float
__device__ inline float quantv(float x, float s) {
  float q = rintf(x / s);
  return fminf(fmaxf(q, -128.0f), 127.0f);
}

__device__ inline float slot_scale(const unsigned int* slots, int i) {
  return fmaxf(__uint_as_float(slots[i]) / 127.0f, 1e-8f);
}

// integer-valued float in [-128,127] -> bf16 bits (exact)
__device__ inline unsigned short f2bf(float x) {
  return (unsigned short)(__float_as_uint(x) >> 16);
}

// ---------------- absmax reduction ----------------
__global__ __launch_bounds__(256) void absmax_k(const float* __restrict__ x, size_t n,
                                                unsigned int* __restrict__ slot) {
  float m = 0.0f;
  for (size_t i = (size_t)blockIdx.x * 256 + threadIdx.x; i < n; i += (size_t)gridDim.x * 256)
    m = fmaxf(m, fabsf(x[i]));
  __shared__ float red[256];
  red[threadIdx.x] = m;
  __syncthreads();
  for (int o = 128; o > 0; o >>= 1) {
    if (threadIdx.x < o) red[threadIdx.x] = fmaxf(red[threadIdx.x], red[threadIdx.x + o]);
    __syncthreads();
  }
  if (threadIdx.x == 0) atomicMax(slot, __float_as_uint(red[0]));
}

// ---------------- quantize-on-load GEMM (fp32 VALU) ----------------
__global__ __launch_bounds__(256) void gemm_quant(const float* __restrict__ A,
                                                  const float* __restrict__ Bw,
                                                  float* __restrict__ C, int M, int N, int K,
                                                  const unsigned int* __restrict__ slots,
                                                  int ia, int ib) {
  __shared__ float As[16][65];
  __shared__ float Bs[16][65];
  const float sa = slot_scale(slots, ia);
  const float sb = slot_scale(slots, ib);
  const int tid = threadIdx.x;
  const int tx = tid & 15, ty = tid >> 4;
  const int n0 = blockIdx.x * 64, m0 = blockIdx.y * 64;
  const int lr = tid >> 2;
  const int lc = (tid & 3) * 4;
  float acc[4][4] = {{0.f}};
  for (int kt = 0; kt < K; kt += 16) {
    const float* ap = A + (size_t)(m0 + lr) * K + kt + lc;
    const float* bp = Bw + (size_t)(n0 + lr) * K + kt + lc;
#pragma unroll
    for (int i = 0; i < 4; i++) As[lc + i][lr] = quantv(ap[i], sa);
#pragma unroll
    for (int i = 0; i < 4; i++) Bs[lc + i][lr] = quantv(bp[i], sb);
    __syncthreads();
#pragma unroll
    for (int k = 0; k < 16; k++) {
      float av[4], bv[4];
#pragma unroll
      for (int i = 0; i < 4; i++) av[i] = As[k][ty * 4 + i];
#pragma unroll
      for (int j = 0; j < 4; j++) bv[j] = Bs[k][tx * 4 + j];
#pragma unroll
      for (int i = 0; i < 4; i++)
#pragma unroll
        for (int j = 0; j < 4; j++) acc[i][j] += av[i] * bv[j];
    }
    __syncthreads();
  }
  const float sc = sa * sb;
#pragma unroll
  for (int i = 0; i < 4; i++)
#pragma unroll
    for (int j = 0; j < 4; j++)
      C[(size_t)(m0 + ty * 4 + i) * N + (n0 + tx * 4 + j)] = acc[i][j] * sc;
}

// ---------------- RoPE in-place + absmax ----------------
__global__ __launch_bounds__(256) void rope_kernel(float* __restrict__ t, int nh,
                                                   unsigned int* __restrict__ slot) {
  size_t idx = (size_t)blockIdx.x * 256 + threadIdx.x;
  size_t total = (size_t)BATCH * SEQ * nh * (HD / 2);
  float am = 0.0f;
  if (idx < total) {
    int i = (int)(idx & 63);
    int h = (int)((idx >> 6) % nh);
    int s = (int)((idx / (64ull * nh)) % SEQ);
    int b = (int)(idx / (64ull * nh * SEQ));
    size_t base = ((size_t)(b * SEQ + s) * nh + h) * HD;
    float inv = 1.0f / powf(10000.0f, (float)(2 * i) * (1.0f / 128.0f));
    float fr = (float)s * inv;
    float c = cosf(fr), sn = sinf(fr);
    float x1 = t[base + i], x2 = t[base + i + 64];
    float r1 = x1 * c - x2 * sn;
    float r2 = x2 * c + x1 * sn;
    t[base + i] = r1;
    t[base + i + 64] = r2;
    am = fmaxf(fabsf(r1), fabsf(r2));
  }
  __shared__ float red[256];
  red[threadIdx.x] = am;
  __syncthreads();
  for (int o = 128; o > 0; o >>= 1) {
    if (threadIdx.x < o) red[threadIdx.x] = fmaxf(red[threadIdx.x], red[threadIdx.x + o]);
    __syncthreads();
  }
  if (threadIdx.x == 0) atomicMax(slot, __float_as_uint(red[0]));
}

// ---------------- quantize fp32 -> integer-valued bf16 ----------------
__global__ __launch_bounds__(256) void quant_bf16_k(const float* __restrict__ x, size_t n,
                                                    const unsigned int* __restrict__ slot,
                                                    unsigned short* __restrict__ out) {
  float s = fmaxf(__uint_as_float(*slot) / 127.0f, 1e-8f);
  for (size_t i = (size_t)blockIdx.x * 256 + threadIdx.x; i < n; i += (size_t)gridDim.x * 256)
    out[i] = f2bf(quantv(x[i], s));
}

// ---------------- MFMA two-pass causal attention ----------------
#define TK 64
#define KS_STRIDE (HD + 8)
#define VT_STRIDE (TK + 8)
#define PS_STRIDE (TK + 8)

__global__ __launch_bounds__(256) void attn_mfma_kernel(const unsigned short* __restrict__ qb,
                                                        const unsigned short* __restrict__ kb,
                                                        const unsigned short* __restrict__ vb,
                                                        float* __restrict__ ob,
                                                        unsigned int* __restrict__ slots) {
  __shared__ unsigned short Ks[TK * KS_STRIDE];
  __shared__ unsigned short Vt[HD * VT_STRIDE];
  __shared__ unsigned short Ps[4 * 16 * PS_STRIDE];
  __shared__ float red[256];

  const int tid = threadIdx.x;
  const int wave = tid >> 6;
  const int lane = tid & 63;
  const int l16 = lane & 15;
  const int quad = lane >> 4;
  const int q0 = blockIdx.x * 64;
  const int h = blockIdx.y;
  const int b = blockIdx.z;
  const int hk = h / GROUPS;
  const int nt = q0 / TK + 1;

  const float s_q = slot_scale(slots, 5);
  const float s_k = slot_scale(slots, 6);
  const float s_v = slot_scale(slots, 7);
  const float sscale = s_q * s_k / 11.313708498984761f;  // /sqrt(128)
  const float scale_p = 1.0f / 127.0f;

  bf16x8 qf[4];
  {
    const unsigned short* qp =
        qb + ((size_t)(b * SEQ + q0 + wave * 16 + l16) * NH + h) * HD + quad * 8;
#pragma unroll
    for (int s = 0; s < 4; s++) qf[s] = *(const bf16x8*)(qp + s * 32);
  }
  const int qrow_base = q0 + wave * 16 + quad * 4;  // + reg r

  // ---- Pass A: online per-row m, l ----
  float m_r[4], l_r[4];
#pragma unroll
  for (int r = 0; r < 4; r++) { m_r[r] = NEG_BIG; l_r[r] = 0.0f; }

  for (int t = 0; t < nt; t++) {
    const int j0 = t * TK;
    __syncthreads();
#pragma unroll
    for (int it = 0; it < 4; it++) {  // stage FULL K tile: 64 rows x 128 d
      int c2 = tid + it * 256;        // 0..1023
      int rr = c2 >> 4;               // 0..63
      int c = c2 & 15;                // 0..15 (d-chunks of 8)
      const unsigned short* src = kb + ((size_t)(b * SEQ + j0 + rr) * NKV + hk) * HD + c * 8;
      *(bf16x8*)(&Ks[rr * KS_STRIDE + c * 8]) = *(const bf16x8*)src;
    }
    __syncthreads();
    f32x4 sfr[4];
#pragma unroll
    for (int kt = 0; kt < 4; kt++) {
      f32x4 acc = {0.f, 0.f, 0.f, 0.f};
      const unsigned short* kp = &Ks[(kt * 16 + l16) * KS_STRIDE + quad * 8];
#pragma unroll
      for (int s = 0; s < 4; s++)
        acc = __builtin_amdgcn_mfma_f32_16x16x32_bf16(qf[s], *(const bf16x8*)(kp + s * 32),
                                                      acc, 0, 0, 0);
      sfr[kt] = acc;
    }
#pragma unroll
    for (int r = 0; r < 4; r++) {
      float sv[4];
      float rowmax = NEG_BIG;
#pragma unroll
      for (int kt = 0; kt < 4; kt++) {
        int key = j0 + kt * 16 + l16;
        float s = sfr[kt][r] * sscale;
        s = (key <= qrow_base + r) ? s : NEG_BIG;
        sv[kt] = s;
        rowmax = fmaxf(rowmax, s);
      }
#pragma unroll
      for (int off = 1; off < 16; off <<= 1) rowmax = fmaxf(rowmax, __shfl_xor(rowmax, off));
      float mn = fmaxf(m_r[r], rowmax);
      float sum = 0.0f;
#pragma unroll
      for (int kt = 0; kt < 4; kt++) sum += expf(sv[kt] - mn);
#pragma unroll
      for (int off = 1; off < 16; off <<= 1) sum += __shfl_xor(sum, off);
      l_r[r] = l_r[r] * expf(m_r[r] - mn) + sum;
      m_r[r] = mn;
    }
  }
#pragma unroll
  for (int r = 0; r < 4; r++) l_r[r] = fmaxf(l_r[r], 1e-30f);

  // ---- Pass B: recompute S, quantize P, PV ----
  f32x4 of[8];
#pragma unroll
  for (int n = 0; n < 8; n++) of[n] = (f32x4){0.f, 0.f, 0.f, 0.f};

  for (int t = 0; t < nt; t++) {
    const int j0 = t * TK;
    __syncthreads();
#pragma unroll
    for (int it = 0; it < 4; it++) {  // stage FULL K tile: 64 rows x 128 d
      int c2 = tid + it * 256;
      int rr = c2 >> 4;
      int c = c2 & 15;
      const unsigned short* src = kb + ((size_t)(b * SEQ + j0 + rr) * NKV + hk) * HD + c * 8;
      *(bf16x8*)(&Ks[rr * KS_STRIDE + c * 8]) = *(const bf16x8*)src;
    }
#pragma unroll
    for (int it = 0; it < 4; it++) {  // stage V tile transposed: Vt[d][kk]
      int idx = tid + it * 256;
      int dc = idx >> 6;
      int kk = idx & 63;
      const unsigned short* src = vb + ((size_t)(b * SEQ + j0 + kk) * NKV + hk) * HD + dc * 8;
      bf16x8 v8 = *(const bf16x8*)src;
#pragma unroll
      for (int j = 0; j < 8; j++) Vt[(dc * 8 + j) * VT_STRIDE + kk] = ((unsigned short*)&v8)[j];
    }
    __syncthreads();
    f32x4 sfr[4];
#pragma unroll
    for (int kt = 0; kt < 4; kt++) {
      f32x4 acc = {0.f, 0.f, 0.f, 0.f};
      const unsigned short* kp = &Ks[(kt * 16 + l16) * KS_STRIDE + quad * 8];
#pragma unroll
      for (int s = 0; s < 4; s++)
        acc = __builtin_amdgcn_mfma_f32_16x16x32_bf16(qf[s], *(const bf16x8*)(kp + s * 32),
                                                      acc, 0, 0, 0);
      sfr[kt] = acc;
    }
#pragma unroll
    for (int kt = 0; kt < 4; kt++) {
#pragma unroll
      for (int r = 0; r < 4; r++) {
        int key = j0 + kt * 16 + l16;
        float p = 0.0f;
        if (key <= qrow_base + r) {
          float e = expf(sfr[kt][r] * sscale - m_r[r]);
          float ratio = fminf(e / l_r[r], 1.0f);
          p = fminf(rintf(ratio / scale_p), 127.0f);
        }
        Ps[(wave * 16 + quad * 4 + r) * PS_STRIDE + kt * 16 + l16] = f2bf(p);
      }
    }
    __syncthreads();  // Ps C-layout writes -> A-layout reads (cross-lane)
    bf16x8 pf[2];
    {
      const unsigned short* pp = &Ps[(wave * 16 + l16) * PS_STRIDE + quad * 8];
      pf[0] = *(const bf16x8*)pp;
      pf[1] = *(const bf16x8*)(pp + 32);
    }
#pragma unroll
    for (int n = 0; n < 8; n++) {
      const unsigned short* vp = &Vt[(n * 16 + l16) * VT_STRIDE + quad * 8];
      of[n] = __builtin_amdgcn_mfma_f32_16x16x32_bf16(pf[0], *(const bf16x8*)vp, of[n], 0, 0, 0);
      of[n] = __builtin_amdgcn_mfma_f32_16x16x32_bf16(pf[1], *(const bf16x8*)(vp + 32), of[n],
                                                      0, 0, 0);
    }
  }

  // ---- epilogue: scale, store, fused absmax ----
  const float oscale = scale_p * s_v;
  float amax = 0.0f;
#pragma unroll
  for (int n = 0; n < 8; n++) {
#pragma unroll
    for (int r = 0; r < 4; r++) {
      float v = of[n][r] * oscale;
      ob[((size_t)(b * SEQ + qrow_base + r) * NH + h) * HD + n * 16 + l16] = v;
      amax = fmaxf(amax, fabsf(v));
    }
  }
  __syncthreads();
  red[tid] = amax;
  __syncthreads();
  for (int o = 128; o > 0; o >>= 1) {
    if (tid < o) red[tid] = fmaxf(red[tid], red[tid + o]);
    __syncthreads();
  }
  if (tid == 0) atomicMax(&slots[8], __float_as_uint(red[0]));
}

extern "C" void kernel_launch(void* const* d_in, const int* in_sizes, int n_in,
                              void* d_out, int out_size, void* d_ws, size_t ws_size,
                              hipStream_t stream) {
  const float* hs = (const float*)d_in[0];
  const float* wq = (const float*)d_in[3];
  const float* wk = (const float*)d_in[4];
  const float* wv = (const float*)d_in[5];
  const float* wo = (const float*)d_in[6];
  float* out = (float*)d_out;

  const size_t nQ = (size_t)BATCH * SEQ * NH * HD;
  const size_t nKV = (size_t)BATCH * SEQ * NKV * HD;

  unsigned int* slots = (unsigned int*)d_ws;
  char* p = (char*)d_ws + 256;
  unsigned short* qbf = (unsigned short*)p;  p += 2 * nQ;
  unsigned short* kbf = (unsigned short*)p;  p += 2 * nKV;
  unsigned short* vbf = (unsigned short*)p;  p += 2 * nKV;
  float* qbuf = (float*)p;                   p += 4 * nQ;
  float* kbuf = (float*)p;                   p += 4 * nKV;
  float* vbuf = (float*)p;
  float* aobuf = qbuf;  // alias: fp32 q dead after quant_bf16_k

  hipMemsetAsync(d_ws, 0, 256, stream);

  const size_t n_hs = (size_t)BATCH * SEQ * HID;
  const size_t n_wq = (size_t)NH * HD * HID;
  const size_t n_wkv = (size_t)NKV * HD * HID;
  const size_t n_wo = (size_t)HID * NH * HD;
  // slots: 0=x 1=wq 2=wk 3=wv 4=wo 5=q 6=k 7=v 8=ao
  absmax_k<<<1024, 256, 0, stream>>>(hs, n_hs, slots + 0);
  absmax_k<<<512, 256, 0, stream>>>(wq, n_wq, slots + 1);
  absmax_k<<<256, 256, 0, stream>>>(wk, n_wkv, slots + 2);
  absmax_k<<<256, 256, 0, stream>>>(wv, n_wkv, slots + 3);
  absmax_k<<<512, 256, 0, stream>>>(wo, n_wo, slots + 4);

  const int M = BATCH * SEQ;
  gemm_quant<<<dim3((NH * HD) / 64, M / 64), 256, 0, stream>>>(hs, wq, qbuf, M, NH * HD, HID,
                                                               slots, 0, 1);
  gemm_quant<<<dim3((NKV * HD) / 64, M / 64), 256, 0, stream>>>(hs, wk, kbuf, M, NKV * HD, HID,
                                                                slots, 0, 2);
  gemm_quant<<<dim3((NKV * HD) / 64, M / 64), 256, 0, stream>>>(hs, wv, vbuf, M, NKV * HD, HID,
                                                                slots, 0, 3);

  rope_kernel<<<(BATCH * SEQ * NH * (HD / 2)) / 256, 256, 0, stream>>>(qbuf, NH, slots + 5);
  rope_kernel<<<(BATCH * SEQ * NKV * (HD / 2)) / 256, 256, 0, stream>>>(kbuf, NKV, slots + 6);
  absmax_k<<<256, 256, 0, stream>>>(vbuf, nKV, slots + 7);

  quant_bf16_k<<<2048, 256, 0, stream>>>(qbuf, nQ, slots + 5, qbf);
  quant_bf16_k<<<1024, 256, 0, stream>>>(kbuf, nKV, slots + 6, kbf);
  quant_bf16_k<<<1024, 256, 0, stream>>>(vbuf, nKV, slots + 7, vbf);

  attn_mfma_kernel<<<dim3(SEQ / 64, NH, BATCH), 256, 0, stream>>>(qbf, kbf, vbf, aobuf, slots);

  gemm_quant<<<dim3(HID / 64, M / 64), 256, 0, stream>>>(aobuf, wo, out, M, HID, NH * HD,
                                                         slots, 8, 4);
}

// Round 6
// 1113.641 us; speedup vs baseline: 7.1231x; 2.5098x over previous
//
#include <hip/hip_runtime.h>
#include <math.h>
#include <stdint.h>
#include <stddef.h>

#define HID 2048
#define NH 16
#define NKV 4
#define HD 128
#define GROUPS (NH / NKV)
#define BATCH 2
#define SEQ 2048

#define NEG_BIG (-3.0e38f)

typedef __attribute__((ext_vector_type(8))) short bf16x8;
typedef __attribute__((ext_vector_type(4))) float f32x4;

// clip(round(x/s), -128, 127) -> integer-valued float
__device__ inline float quantv(float x, float s) {
  float q = rintf(x / s);
  return fminf(fmaxf(q, -128.0f), 127.0f);
}

__device__ inline float slot_scale(const unsigned int* slots, int i) {
  return fmaxf(__uint_as_float(slots[i]) / 127.0f, 1e-8f);
}

// integer-valued float in [-128,127] -> bf16 bits (exact)
__device__ inline unsigned short f2bf(float x) {
  return (unsigned short)(__float_as_uint(x) >> 16);
}

// ---------------- absmax reduction ----------------
__global__ __launch_bounds__(256) void absmax_k(const float* __restrict__ x, size_t n,
                                                unsigned int* __restrict__ slot) {
  float m = 0.0f;
  for (size_t i = (size_t)blockIdx.x * 256 + threadIdx.x; i < n; i += (size_t)gridDim.x * 256)
    m = fmaxf(m, fabsf(x[i]));
  __shared__ float red[256];
  red[threadIdx.x] = m;
  __syncthreads();
  for (int o = 128; o > 0; o >>= 1) {
    if (threadIdx.x < o) red[threadIdx.x] = fmaxf(red[threadIdx.x], red[threadIdx.x + o]);
    __syncthreads();
  }
  if (threadIdx.x == 0) atomicMax(slot, __float_as_uint(red[0]));
}

// ---------------- quantize fp32 -> integer-valued bf16 ----------------
__global__ __launch_bounds__(256) void quant_bf16_k(const float* __restrict__ x, size_t n,
                                                    const unsigned int* __restrict__ slot,
                                                    unsigned short* __restrict__ out) {
  float s = fmaxf(__uint_as_float(*slot) / 127.0f, 1e-8f);
  for (size_t i = (size_t)blockIdx.x * 256 + threadIdx.x; i < n; i += (size_t)gridDim.x * 256)
    out[i] = f2bf(quantv(x[i], s));
}

// ---------------- MFMA GEMM: C[m,n] = sa*sb * sum_k A[m,k]*B[n,k] ----------------
// A: [M,K] bf16 (integer-valued), B: [N,K] bf16 (B^T layout), C: [M,N] fp32.
// 128x128 tile, BK=32, 4 waves each computing 64x64 via 4x4 grid of 16x16x32 MFMA.
__global__ __launch_bounds__(256) void gemm_bt_mfma(const unsigned short* __restrict__ A,
                                                    const unsigned short* __restrict__ B,
                                                    float* __restrict__ C, int M, int N, int K,
                                                    const unsigned int* __restrict__ slots,
                                                    int ia, int ib) {
  __shared__ unsigned short As[128 * 32];  // unpadded: bank-balanced for b128 reads
  __shared__ unsigned short Bs[128 * 32];
  const int tid = threadIdx.x;
  const int wave = tid >> 6, lane = tid & 63;
  const int l16 = lane & 15, quad = lane >> 4;
  const int n0 = blockIdx.x * 128, m0 = blockIdx.y * 128;
  const int wm = (wave & 1) * 64, wn = (wave >> 1) * 64;
  const float sc = slot_scale(slots, ia) * slot_scale(slots, ib);

  f32x4 acc[4][4];
#pragma unroll
  for (int i = 0; i < 4; i++)
#pragma unroll
    for (int j = 0; j < 4; j++) acc[i][j] = (f32x4){0.f, 0.f, 0.f, 0.f};

  for (int kt = 0; kt < K; kt += 32) {
    __syncthreads();
#pragma unroll
    for (int it = 0; it < 2; it++) {
      int c = it * 256 + tid;       // 0..511 chunks of 8 bf16
      int row = c >> 2;             // 0..127
      int kc = (c & 3) * 8;         // 0,8,16,24
      *(bf16x8*)(&As[row * 32 + kc]) =
          *(const bf16x8*)(A + (size_t)(m0 + row) * K + kt + kc);
      *(bf16x8*)(&Bs[row * 32 + kc]) =
          *(const bf16x8*)(B + (size_t)(n0 + row) * K + kt + kc);
    }
    __syncthreads();
    bf16x8 af[4], bf[4];
#pragma unroll
    for (int i = 0; i < 4; i++)
      af[i] = *(const bf16x8*)(&As[(wm + i * 16 + l16) * 32 + quad * 8]);
#pragma unroll
    for (int j = 0; j < 4; j++)
      bf[j] = *(const bf16x8*)(&Bs[(wn + j * 16 + l16) * 32 + quad * 8]);
#pragma unroll
    for (int i = 0; i < 4; i++)
#pragma unroll
      for (int j = 0; j < 4; j++)
        acc[i][j] = __builtin_amdgcn_mfma_f32_16x16x32_bf16(af[i], bf[j], acc[i][j], 0, 0, 0);
  }

#pragma unroll
  for (int i = 0; i < 4; i++) {
#pragma unroll
    for (int j = 0; j < 4; j++) {
#pragma unroll
      for (int r = 0; r < 4; r++) {
        int row = m0 + wm + i * 16 + quad * 4 + r;
        int col = n0 + wn + j * 16 + l16;
        C[(size_t)row * N + col] = acc[i][j][r] * sc;
      }
    }
  }
}

// ---------------- RoPE in-place + absmax ----------------
__global__ __launch_bounds__(256) void rope_kernel(float* __restrict__ t, int nh,
                                                   unsigned int* __restrict__ slot) {
  size_t idx = (size_t)blockIdx.x * 256 + threadIdx.x;
  size_t total = (size_t)BATCH * SEQ * nh * (HD / 2);
  float am = 0.0f;
  if (idx < total) {
    int i = (int)(idx & 63);
    int h = (int)((idx >> 6) % nh);
    int s = (int)((idx / (64ull * nh)) % SEQ);
    int b = (int)(idx / (64ull * nh * SEQ));
    size_t base = ((size_t)(b * SEQ + s) * nh + h) * HD;
    float inv = 1.0f / powf(10000.0f, (float)(2 * i) * (1.0f / 128.0f));
    float fr = (float)s * inv;
    float c = cosf(fr), sn = sinf(fr);
    float x1 = t[base + i], x2 = t[base + i + 64];
    float r1 = x1 * c - x2 * sn;
    float r2 = x2 * c + x1 * sn;
    t[base + i] = r1;
    t[base + i + 64] = r2;
    am = fmaxf(fabsf(r1), fabsf(r2));
  }
  __shared__ float red[256];
  red[threadIdx.x] = am;
  __syncthreads();
  for (int o = 128; o > 0; o >>= 1) {
    if (threadIdx.x < o) red[threadIdx.x] = fmaxf(red[threadIdx.x], red[threadIdx.x + o]);
    __syncthreads();
  }
  if (threadIdx.x == 0) atomicMax(slot, __float_as_uint(red[0]));
}

// ---------------- MFMA two-pass causal attention (unchanged from R5, verified) ----------------
#define TK 64
#define KS_STRIDE (HD + 8)
#define VT_STRIDE (TK + 8)
#define PS_STRIDE (TK + 8)

__global__ __launch_bounds__(256) void attn_mfma_kernel(const unsigned short* __restrict__ qb,
                                                        const unsigned short* __restrict__ kb,
                                                        const unsigned short* __restrict__ vb,
                                                        float* __restrict__ ob,
                                                        unsigned int* __restrict__ slots) {
  __shared__ unsigned short Ks[TK * KS_STRIDE];
  __shared__ unsigned short Vt[HD * VT_STRIDE];
  __shared__ unsigned short Ps[4 * 16 * PS_STRIDE];
  __shared__ float red[256];

  const int tid = threadIdx.x;
  const int wave = tid >> 6;
  const int lane = tid & 63;
  const int l16 = lane & 15;
  const int quad = lane >> 4;
  const int q0 = blockIdx.x * 64;
  const int h = blockIdx.y;
  const int b = blockIdx.z;
  const int hk = h / GROUPS;
  const int nt = q0 / TK + 1;

  const float s_q = slot_scale(slots, 5);
  const float s_k = slot_scale(slots, 6);
  const float s_v = slot_scale(slots, 7);
  const float sscale = s_q * s_k / 11.313708498984761f;  // /sqrt(128)
  const float scale_p = 1.0f / 127.0f;

  bf16x8 qf[4];
  {
    const unsigned short* qp =
        qb + ((size_t)(b * SEQ + q0 + wave * 16 + l16) * NH + h) * HD + quad * 8;
#pragma unroll
    for (int s = 0; s < 4; s++) qf[s] = *(const bf16x8*)(qp + s * 32);
  }
  const int qrow_base = q0 + wave * 16 + quad * 4;  // + reg r

  // ---- Pass A: online per-row m, l ----
  float m_r[4], l_r[4];
#pragma unroll
  for (int r = 0; r < 4; r++) { m_r[r] = NEG_BIG; l_r[r] = 0.0f; }

  for (int t = 0; t < nt; t++) {
    const int j0 = t * TK;
    __syncthreads();
#pragma unroll
    for (int it = 0; it < 4; it++) {  // stage FULL K tile: 64 rows x 128 d
      int c2 = tid + it * 256;
      int rr = c2 >> 4;
      int c = c2 & 15;
      const unsigned short* src = kb + ((size_t)(b * SEQ + j0 + rr) * NKV + hk) * HD + c * 8;
      *(bf16x8*)(&Ks[rr * KS_STRIDE + c * 8]) = *(const bf16x8*)src;
    }
    __syncthreads();
    f32x4 sfr[4];
#pragma unroll
    for (int kt = 0; kt < 4; kt++) {
      f32x4 acc = {0.f, 0.f, 0.f, 0.f};
      const unsigned short* kp = &Ks[(kt * 16 + l16) * KS_STRIDE + quad * 8];
#pragma unroll
      for (int s = 0; s < 4; s++)
        acc = __builtin_amdgcn_mfma_f32_16x16x32_bf16(qf[s], *(const bf16x8*)(kp + s * 32),
                                                      acc, 0, 0, 0);
      sfr[kt] = acc;
    }
#pragma unroll
    for (int r = 0; r < 4; r++) {
      float sv[4];
      float rowmax = NEG_BIG;
#pragma unroll
      for (int kt = 0; kt < 4; kt++) {
        int key = j0 + kt * 16 + l16;
        float s = sfr[kt][r] * sscale;
        s = (key <= qrow_base + r) ? s : NEG_BIG;
        sv[kt] = s;
        rowmax = fmaxf(rowmax, s);
      }
#pragma unroll
      for (int off = 1; off < 16; off <<= 1) rowmax = fmaxf(rowmax, __shfl_xor(rowmax, off));
      float mn = fmaxf(m_r[r], rowmax);
      float sum = 0.0f;
#pragma unroll
      for (int kt = 0; kt < 4; kt++) sum += expf(sv[kt] - mn);
#pragma unroll
      for (int off = 1; off < 16; off <<= 1) sum += __shfl_xor(sum, off);
      l_r[r] = l_r[r] * expf(m_r[r] - mn) + sum;
      m_r[r] = mn;
    }
  }
#pragma unroll
  for (int r = 0; r < 4; r++) l_r[r] = fmaxf(l_r[r], 1e-30f);

  // ---- Pass B: recompute S, quantize P, PV ----
  f32x4 of[8];
#pragma unroll
  for (int n = 0; n < 8; n++) of[n] = (f32x4){0.f, 0.f, 0.f, 0.f};

  for (int t = 0; t < nt; t++) {
    const int j0 = t * TK;
    __syncthreads();
#pragma unroll
    for (int it = 0; it < 4; it++) {
      int c2 = tid + it * 256;
      int rr = c2 >> 4;
      int c = c2 & 15;
      const unsigned short* src = kb + ((size_t)(b * SEQ + j0 + rr) * NKV + hk) * HD + c * 8;
      *(bf16x8*)(&Ks[rr * KS_STRIDE + c * 8]) = *(const bf16x8*)src;
    }
#pragma unroll
    for (int it = 0; it < 4; it++) {
      int idx = tid + it * 256;
      int dc = idx >> 6;
      int kk = idx & 63;
      const unsigned short* src = vb + ((size_t)(b * SEQ + j0 + kk) * NKV + hk) * HD + dc * 8;
      bf16x8 v8 = *(const bf16x8*)src;
#pragma unroll
      for (int j = 0; j < 8; j++) Vt[(dc * 8 + j) * VT_STRIDE + kk] = ((unsigned short*)&v8)[j];
    }
    __syncthreads();
    f32x4 sfr[4];
#pragma unroll
    for (int kt = 0; kt < 4; kt++) {
      f32x4 acc = {0.f, 0.f, 0.f, 0.f};
      const unsigned short* kp = &Ks[(kt * 16 + l16) * KS_STRIDE + quad * 8];
#pragma unroll
      for (int s = 0; s < 4; s++)
        acc = __builtin_amdgcn_mfma_f32_16x16x32_bf16(qf[s], *(const bf16x8*)(kp + s * 32),
                                                      acc, 0, 0, 0);
      sfr[kt] = acc;
    }
#pragma unroll
    for (int kt = 0; kt < 4; kt++) {
#pragma unroll
      for (int r = 0; r < 4; r++) {
        int key = j0 + kt * 16 + l16;
        float p = 0.0f;
        if (key <= qrow_base + r) {
          float e = expf(sfr[kt][r] * sscale - m_r[r]);
          float ratio = fminf(e / l_r[r], 1.0f);
          p = fminf(rintf(ratio / scale_p), 127.0f);
        }
        Ps[(wave * 16 + quad * 4 + r) * PS_STRIDE + kt * 16 + l16] = f2bf(p);
      }
    }
    __syncthreads();  // Ps C-layout writes -> A-layout reads (cross-lane)
    bf16x8 pf[2];
    {
      const unsigned short* pp = &Ps[(wave * 16 + l16) * PS_STRIDE + quad * 8];
      pf[0] = *(const bf16x8*)pp;
      pf[1] = *(const bf16x8*)(pp + 32);
    }
#pragma unroll
    for (int n = 0; n < 8; n++) {
      const unsigned short* vp = &Vt[(n * 16 + l16) * VT_STRIDE + quad * 8];
      of[n] = __builtin_amdgcn_mfma_f32_16x16x32_bf16(pf[0], *(const bf16x8*)vp, of[n], 0, 0, 0);
      of[n] = __builtin_amdgcn_mfma_f32_16x16x32_bf16(pf[1], *(const bf16x8*)(vp + 32), of[n],
                                                      0, 0, 0);
    }
  }

  // ---- epilogue: scale, store, fused absmax ----
  const float oscale = scale_p * s_v;
  float amax = 0.0f;
#pragma unroll
  for (int n = 0; n < 8; n++) {
#pragma unroll
    for (int r = 0; r < 4; r++) {
      float v = of[n][r] * oscale;
      ob[((size_t)(b * SEQ + qrow_base + r) * NH + h) * HD + n * 16 + l16] = v;
      amax = fmaxf(amax, fabsf(v));
    }
  }
  __syncthreads();
  red[tid] = amax;
  __syncthreads();
  for (int o = 128; o > 0; o >>= 1) {
    if (tid < o) red[tid] = fmaxf(red[tid], red[tid + o]);
    __syncthreads();
  }
  if (tid == 0) atomicMax(&slots[8], __float_as_uint(red[0]));
}

extern "C" void kernel_launch(void* const* d_in, const int* in_sizes, int n_in,
                              void* d_out, int out_size, void* d_ws, size_t ws_size,
                              hipStream_t stream) {
  const float* hs = (const float*)d_in[0];
  const float* wq = (const float*)d_in[3];
  const float* wk = (const float*)d_in[4];
  const float* wv = (const float*)d_in[5];
  const float* wo = (const float*)d_in[6];
  float* out = (float*)d_out;

  const size_t nHS = (size_t)BATCH * SEQ * HID;    // 8M (== nQ)
  const size_t nQ = (size_t)BATCH * SEQ * NH * HD; // 8M
  const size_t nKV = (size_t)BATCH * SEQ * NKV * HD; // 2M
  const size_t nWQ = (size_t)NH * HD * HID;        // 4M
  const size_t nWKV = (size_t)NKV * HD * HID;      // 1M
  const size_t nWO = (size_t)HID * NH * HD;        // 4M

  // ws layout (79.7 MB total; fp32 q-proj output & fp32 attn output live in d_out):
  unsigned int* slots = (unsigned int*)d_ws;
  char* p = (char*)d_ws + 256;
  unsigned short* hsq = (unsigned short*)p;  p += 2 * nHS;   // dead after proj GEMMs
  unsigned short* wqq = (unsigned short*)p;  p += 2 * nWQ;
  unsigned short* wkq = (unsigned short*)p;  p += 2 * nWKV;
  unsigned short* wvq = (unsigned short*)p;  p += 2 * nWKV;
  unsigned short* woq = (unsigned short*)p;  p += 2 * nWO;
  float* kbuf = (float*)p;                   p += 4 * nKV;
  float* vbuf = (float*)p;                   p += 4 * nKV;
  unsigned short* qbf = (unsigned short*)p;  p += 2 * nQ;
  unsigned short* kbf = (unsigned short*)p;  p += 2 * nKV;
  unsigned short* vbf = (unsigned short*)p;
  unsigned short* aobf = hsq;   // alias: hsq dead after V-proj GEMM
  float* qbuf = out;            // fp32 q-proj output lives in d_out (rope in-place)
  float* aobuf = out;           // fp32 attn output lives in d_out (qbuf dead by then)

  hipMemsetAsync(d_ws, 0, 256, stream);

  // slots: 0=x 1=wq 2=wk 3=wv 4=wo 5=q 6=k 7=v 8=ao
  absmax_k<<<1024, 256, 0, stream>>>(hs, nHS, slots + 0);
  absmax_k<<<512, 256, 0, stream>>>(wq, nWQ, slots + 1);
  absmax_k<<<256, 256, 0, stream>>>(wk, nWKV, slots + 2);
  absmax_k<<<256, 256, 0, stream>>>(wv, nWKV, slots + 3);
  absmax_k<<<512, 256, 0, stream>>>(wo, nWO, slots + 4);

  quant_bf16_k<<<2048, 256, 0, stream>>>(hs, nHS, slots + 0, hsq);
  quant_bf16_k<<<1024, 256, 0, stream>>>(wq, nWQ, slots + 1, wqq);
  quant_bf16_k<<<512, 256, 0, stream>>>(wk, nWKV, slots + 2, wkq);
  quant_bf16_k<<<512, 256, 0, stream>>>(wv, nWKV, slots + 3, wvq);
  quant_bf16_k<<<1024, 256, 0, stream>>>(wo, nWO, slots + 4, woq);

  const int M = BATCH * SEQ;
  gemm_bt_mfma<<<dim3((NH * HD) / 128, M / 128), 256, 0, stream>>>(hsq, wqq, qbuf, M, NH * HD,
                                                                   HID, slots, 0, 1);
  gemm_bt_mfma<<<dim3((NKV * HD) / 128, M / 128), 256, 0, stream>>>(hsq, wkq, kbuf, M, NKV * HD,
                                                                    HID, slots, 0, 2);
  gemm_bt_mfma<<<dim3((NKV * HD) / 128, M / 128), 256, 0, stream>>>(hsq, wvq, vbuf, M, NKV * HD,
                                                                    HID, slots, 0, 3);

  rope_kernel<<<(BATCH * SEQ * NH * (HD / 2)) / 256, 256, 0, stream>>>(qbuf, NH, slots + 5);
  rope_kernel<<<(BATCH * SEQ * NKV * (HD / 2)) / 256, 256, 0, stream>>>(kbuf, NKV, slots + 6);
  absmax_k<<<256, 256, 0, stream>>>(vbuf, nKV, slots + 7);

  quant_bf16_k<<<2048, 256, 0, stream>>>(qbuf, nQ, slots + 5, qbf);
  quant_bf16_k<<<1024, 256, 0, stream>>>(kbuf, nKV, slots + 6, kbf);
  quant_bf16_k<<<1024, 256, 0, stream>>>(vbuf, nKV, slots + 7, vbf);

  attn_mfma_kernel<<<dim3(SEQ / 64, NH, BATCH), 256, 0, stream>>>(qbf, kbf, vbf, aobuf, slots);

  quant_bf16_k<<<2048, 256, 0, stream>>>(aobuf, nQ, slots + 8, aobf);

  gemm_bt_mfma<<<dim3(HID / 128, M / 128), 256, 0, stream>>>(aobf, woq, out, M, HID, NH * HD,
                                                             slots, 8, 4);
}

// Round 7
// 912.151 us; speedup vs baseline: 8.6966x; 1.2209x over previous
//
#include <hip/hip_runtime.h>
#include <math.h>
#include <stdint.h>
#include <stddef.h>

#define HID 2048
#define NH 16
#define NKV 4
#define HD 128
#define GROUPS (NH / NKV)
#define BATCH 2
#define SEQ 2048

#define N_HS  8388608ull   // B*S*HID
#define N_Q   8388608ull   // B*S*NH*HD
#define N_KV  2097152ull   // B*S*NKV*HD
#define N_WQ  4194304ull
#define N_WKV 1048576ull
#define N_WO  4194304ull

typedef __attribute__((ext_vector_type(8))) short bf16x8;
typedef __attribute__((ext_vector_type(4))) float f32x4;

__device__ inline float quantv(float x, float s) {
  float q = rintf(x / s);
  return fminf(fmaxf(q, -128.0f), 127.0f);
}

__device__ inline float slot_scale(const unsigned int* slots, int i) {
  return fmaxf(__uint_as_float(slots[i]) / 127.0f, 1e-8f);
}

__device__ inline unsigned short f2bf(float x) {
  return (unsigned short)(__float_as_uint(x) >> 16);
}

__device__ inline float amax4(float4 v) {
  return fmaxf(fmaxf(fabsf(v.x), fabsf(v.y)), fmaxf(fabsf(v.z), fabsf(v.w)));
}

__device__ inline void block_amax_atomic(float m, unsigned int* slot) {
  __shared__ float red[256];
  red[threadIdx.x] = m;
  __syncthreads();
  for (int o = 128; o > 0; o >>= 1) {
    if (threadIdx.x < o) red[threadIdx.x] = fmaxf(red[threadIdx.x], red[threadIdx.x + o]);
    __syncthreads();
  }
  if (threadIdx.x == 0) atomicMax(slot, __float_as_uint(red[0]));
}

// ---------------- fused absmax over the 5 input tensors ----------------
__global__ __launch_bounds__(256) void absmax5_k(const float* __restrict__ a0,
                                                 const float* __restrict__ a1,
                                                 const float* __restrict__ a2,
                                                 const float* __restrict__ a3,
                                                 const float* __restrict__ a4,
                                                 unsigned int* __restrict__ slots) {
  const int t = blockIdx.y;
  const float* x = t == 0 ? a0 : t == 1 ? a1 : t == 2 ? a2 : t == 3 ? a3 : a4;
  const size_t n4 = (t == 0 ? N_HS : t == 1 ? N_WQ : t == 2 ? N_WKV : t == 3 ? N_WKV : N_WO) / 4;
  const float4* xp = (const float4*)x;
  float m = 0.0f;
  for (size_t i = (size_t)blockIdx.x * 256 + threadIdx.x; i < n4; i += (size_t)gridDim.x * 256)
    m = fmaxf(m, amax4(xp[i]));
  block_amax_atomic(m, slots + t);
}

// ---------------- fused quantize (fp32 -> integer-valued bf16) over 5 tensors ----------------
__global__ __launch_bounds__(256) void quant5_k(const float* __restrict__ a0,
                                                const float* __restrict__ a1,
                                                const float* __restrict__ a2,
                                                const float* __restrict__ a3,
                                                const float* __restrict__ a4,
                                                const unsigned int* __restrict__ slots,
                                                unsigned short* __restrict__ o0,
                                                unsigned short* __restrict__ o1,
                                                unsigned short* __restrict__ o2,
                                                unsigned short* __restrict__ o3,
                                                unsigned short* __restrict__ o4) {
  const int t = blockIdx.y;
  const float* x = t == 0 ? a0 : t == 1 ? a1 : t == 2 ? a2 : t == 3 ? a3 : a4;
  unsigned short* o = t == 0 ? o0 : t == 1 ? o1 : t == 2 ? o2 : t == 3 ? o3 : o4;
  const size_t n4 = (t == 0 ? N_HS : t == 1 ? N_WQ : t == 2 ? N_WKV : t == 3 ? N_WKV : N_WO) / 4;
  const float s = fmaxf(__uint_as_float(slots[t]) / 127.0f, 1e-8f);
  const float4* xp = (const float4*)x;
  ushort4* op = (ushort4*)o;
  for (size_t i = (size_t)blockIdx.x * 256 + threadIdx.x; i < n4; i += (size_t)gridDim.x * 256) {
    float4 v = xp[i];
    ushort4 r;
    r.x = f2bf(quantv(v.x, s));
    r.y = f2bf(quantv(v.y, s));
    r.z = f2bf(quantv(v.z, s));
    r.w = f2bf(quantv(v.w, s));
    op[i] = r;
  }
}

// ---------------- fused quantize q/k/v ----------------
__global__ __launch_bounds__(256) void quant3_k(const float* __restrict__ a0,
                                                const float* __restrict__ a1,
                                                const float* __restrict__ a2,
                                                const unsigned int* __restrict__ slots,
                                                unsigned short* __restrict__ o0,
                                                unsigned short* __restrict__ o1,
                                                unsigned short* __restrict__ o2) {
  const int t = blockIdx.y;
  const float* x = t == 0 ? a0 : t == 1 ? a1 : a2;
  unsigned short* o = t == 0 ? o0 : t == 1 ? o1 : o2;
  const size_t n4 = (t == 0 ? N_Q : N_KV) / 4;
  const float s = fmaxf(__uint_as_float(slots[5 + t]) / 127.0f, 1e-8f);
  const float4* xp = (const float4*)x;
  ushort4* op = (ushort4*)o;
  for (size_t i = (size_t)blockIdx.x * 256 + threadIdx.x; i < n4; i += (size_t)gridDim.x * 256) {
    float4 v = xp[i];
    ushort4 r;
    r.x = f2bf(quantv(v.x, s));
    r.y = f2bf(quantv(v.y, s));
    r.z = f2bf(quantv(v.z, s));
    r.w = f2bf(quantv(v.w, s));
    op[i] = r;
  }
}

// ---------------- single-tensor vectorized absmax / quant ----------------
__global__ __launch_bounds__(256) void absmax1_k(const float* __restrict__ x, size_t n4,
                                                 unsigned int* __restrict__ slot) {
  const float4* xp = (const float4*)x;
  float m = 0.0f;
  for (size_t i = (size_t)blockIdx.x * 256 + threadIdx.x; i < n4; i += (size_t)gridDim.x * 256)
    m = fmaxf(m, amax4(xp[i]));
  block_amax_atomic(m, slot);
}

__global__ __launch_bounds__(256) void quant1_k(const float* __restrict__ x, size_t n4,
                                                const unsigned int* __restrict__ slot,
                                                unsigned short* __restrict__ out) {
  const float s = fmaxf(__uint_as_float(*slot) / 127.0f, 1e-8f);
  const float4* xp = (const float4*)x;
  ushort4* op = (ushort4*)out;
  for (size_t i = (size_t)blockIdx.x * 256 + threadIdx.x; i < n4; i += (size_t)gridDim.x * 256) {
    float4 v = xp[i];
    ushort4 r;
    r.x = f2bf(quantv(v.x, s));
    r.y = f2bf(quantv(v.y, s));
    r.z = f2bf(quantv(v.z, s));
    r.w = f2bf(quantv(v.w, s));
    op[i] = r;
  }
}

// ---------------- MFMA GEMM (unchanged from R6, verified) ----------------
__global__ __launch_bounds__(256) void gemm_bt_mfma(const unsigned short* __restrict__ A,
                                                    const unsigned short* __restrict__ B,
                                                    float* __restrict__ C, int M, int N, int K,
                                                    const unsigned int* __restrict__ slots,
                                                    int ia, int ib) {
  __shared__ unsigned short As[128 * 32];
  __shared__ unsigned short Bs[128 * 32];
  const int tid = threadIdx.x;
  const int wave = tid >> 6, lane = tid & 63;
  const int l16 = lane & 15, quad = lane >> 4;
  const int n0 = blockIdx.x * 128, m0 = blockIdx.y * 128;
  const int wm = (wave & 1) * 64, wn = (wave >> 1) * 64;
  const float sc = slot_scale(slots, ia) * slot_scale(slots, ib);

  f32x4 acc[4][4];
#pragma unroll
  for (int i = 0; i < 4; i++)
#pragma unroll
    for (int j = 0; j < 4; j++) acc[i][j] = (f32x4){0.f, 0.f, 0.f, 0.f};

  for (int kt = 0; kt < K; kt += 32) {
    __syncthreads();
#pragma unroll
    for (int it = 0; it < 2; it++) {
      int c = it * 256 + tid;
      int row = c >> 2;
      int kc = (c & 3) * 8;
      *(bf16x8*)(&As[row * 32 + kc]) = *(const bf16x8*)(A + (size_t)(m0 + row) * K + kt + kc);
      *(bf16x8*)(&Bs[row * 32 + kc]) = *(const bf16x8*)(B + (size_t)(n0 + row) * K + kt + kc);
    }
    __syncthreads();
    bf16x8 af[4], bf[4];
#pragma unroll
    for (int i = 0; i < 4; i++)
      af[i] = *(const bf16x8*)(&As[(wm + i * 16 + l16) * 32 + quad * 8]);
#pragma unroll
    for (int j = 0; j < 4; j++)
      bf[j] = *(const bf16x8*)(&Bs[(wn + j * 16 + l16) * 32 + quad * 8]);
#pragma unroll
    for (int i = 0; i < 4; i++)
#pragma unroll
      for (int j = 0; j < 4; j++)
        acc[i][j] = __builtin_amdgcn_mfma_f32_16x16x32_bf16(af[i], bf[j], acc[i][j], 0, 0, 0);
  }

#pragma unroll
  for (int i = 0; i < 4; i++)
#pragma unroll
    for (int j = 0; j < 4; j++)
#pragma unroll
      for (int r = 0; r < 4; r++) {
        int row = m0 + wm + i * 16 + quad * 4 + r;
        int col = n0 + wn + j * 16 + l16;
        C[(size_t)row * N + col] = acc[i][j][r] * sc;
      }
}

// ---------------- RoPE in-place + absmax ----------------
__global__ __launch_bounds__(256) void rope_kernel(float* __restrict__ t, int nh,
                                                   unsigned int* __restrict__ slot) {
  size_t idx = (size_t)blockIdx.x * 256 + threadIdx.x;
  size_t total = (size_t)BATCH * SEQ * nh * (HD / 2);
  float am = 0.0f;
  if (idx < total) {
    int i = (int)(idx & 63);
    int h = (int)((idx >> 6) % nh);
    int s = (int)((idx / (64ull * nh)) % SEQ);
    int b = (int)(idx / (64ull * nh * SEQ));
    size_t base = ((size_t)(b * SEQ + s) * nh + h) * HD;
    float inv = 1.0f / powf(10000.0f, (float)(2 * i) * (1.0f / 128.0f));
    float fr = (float)s * inv;
    float c = cosf(fr), sn = sinf(fr);
    float x1 = t[base + i], x2 = t[base + i + 64];
    float r1 = x1 * c - x2 * sn;
    float r2 = x2 * c + x1 * sn;
    t[base + i] = r1;
    t[base + i + 64] = r2;
    am = fmaxf(fabsf(r1), fabsf(r2));
  }
  block_amax_atomic(am, slot);
}

// ---------------- MFMA two-pass causal attention (max-free softmax) ----------------
#define TK 64
#define KS_STRIDE (HD + 8)
#define VT_STRIDE (TK + 8)
#define PS_STRIDE (TK + 8)

__global__ __launch_bounds__(256) void attn_mfma_kernel(const unsigned short* __restrict__ qb,
                                                        const unsigned short* __restrict__ kb,
                                                        const unsigned short* __restrict__ vb,
                                                        float* __restrict__ ob,
                                                        unsigned int* __restrict__ slots) {
  __shared__ unsigned short Ks[TK * KS_STRIDE];
  __shared__ unsigned short Vt[HD * VT_STRIDE];
  __shared__ unsigned short Ps[4 * 16 * PS_STRIDE];

  const int tid = threadIdx.x;
  const int wave = tid >> 6;
  const int lane = tid & 63;
  const int l16 = lane & 15;
  const int quad = lane >> 4;
  // reversed mapping: longest blocks (most K-tiles) dispatch first
  const int q0 = (int)(gridDim.x - 1 - blockIdx.x) * 64;
  const int h = blockIdx.y;
  const int b = blockIdx.z;
  const int hk = h / GROUPS;
  const int nt = q0 / TK + 1;

  const float s_q = slot_scale(slots, 5);
  const float s_k = slot_scale(slots, 6);
  const float s_v = slot_scale(slots, 7);
  const float sscale = s_q * s_k / 11.313708498984761f;  // /sqrt(128)
  const float scale_p = 1.0f / 127.0f;

  bf16x8 qf[4];
  {
    const unsigned short* qp =
        qb + ((size_t)(b * SEQ + q0 + wave * 16 + l16) * NH + h) * HD + quad * 8;
#pragma unroll
    for (int s = 0; s < 4; s++) qf[s] = *(const bf16x8*)(qp + s * 32);
  }
  const int qrow_base = q0 + wave * 16 + quad * 4;  // + reg r

  // ---- Pass A: l = sum(exp(s)) -- no max subtraction (scores bounded; e/l invariant) ----
  float l_r[4] = {0.f, 0.f, 0.f, 0.f};

  for (int t = 0; t < nt; t++) {
    const int j0 = t * TK;
    __syncthreads();
#pragma unroll
    for (int it = 0; it < 4; it++) {  // stage K tile: 64 rows x 128 d
      int c2 = tid + it * 256;
      int rr = c2 >> 4, c = c2 & 15;
      const unsigned short* src = kb + ((size_t)(b * SEQ + j0 + rr) * NKV + hk) * HD + c * 8;
      *(bf16x8*)(&Ks[rr * KS_STRIDE + c * 8]) = *(const bf16x8*)src;
    }
    __syncthreads();
    f32x4 sfr[4];
#pragma unroll
    for (int kt = 0; kt < 4; kt++) {
      f32x4 acc = {0.f, 0.f, 0.f, 0.f};
      const unsigned short* kp = &Ks[(kt * 16 + l16) * KS_STRIDE + quad * 8];
#pragma unroll
      for (int s = 0; s < 4; s++)
        acc = __builtin_amdgcn_mfma_f32_16x16x32_bf16(qf[s], *(const bf16x8*)(kp + s * 32),
                                                      acc, 0, 0, 0);
      sfr[kt] = acc;
    }
    if (t < nt - 1) {  // fully-unmasked tile (wave-uniform branch)
#pragma unroll
      for (int kt = 0; kt < 4; kt++)
#pragma unroll
        for (int r = 0; r < 4; r++)
          l_r[r] += expf(fminf(sfr[kt][r] * sscale, 80.0f));
    } else {  // diagonal tile: causal mask
#pragma unroll
      for (int kt = 0; kt < 4; kt++) {
        const int key = j0 + kt * 16 + l16;
#pragma unroll
        for (int r = 0; r < 4; r++) {
          float e = expf(fminf(sfr[kt][r] * sscale, 80.0f));
          l_r[r] += (key <= qrow_base + r) ? e : 0.0f;
        }
      }
    }
  }
  float il[4];
#pragma unroll
  for (int r = 0; r < 4; r++) {
#pragma unroll
    for (int off = 1; off < 16; off <<= 1) l_r[r] += __shfl_xor(l_r[r], off);
    il[r] = 127.0f / fmaxf(l_r[r], 1e-30f);
  }

  // ---- Pass B: recompute S, quantize P, PV ----
  f32x4 of[8];
#pragma unroll
  for (int n = 0; n < 8; n++) of[n] = (f32x4){0.f, 0.f, 0.f, 0.f};

  for (int t = 0; t < nt; t++) {
    const int j0 = t * TK;
    __syncthreads();
#pragma unroll
    for (int it = 0; it < 4; it++) {
      int c2 = tid + it * 256;
      int rr = c2 >> 4, c = c2 & 15;
      const unsigned short* src = kb + ((size_t)(b * SEQ + j0 + rr) * NKV + hk) * HD + c * 8;
      *(bf16x8*)(&Ks[rr * KS_STRIDE + c * 8]) = *(const bf16x8*)src;
    }
#pragma unroll
    for (int it = 0; it < 4; it++) {  // stage V transposed: Vt[d][kk]
      int idx = tid + it * 256;
      int dc = idx >> 6, kk = idx & 63;
      const unsigned short* src = vb + ((size_t)(b * SEQ + j0 + kk) * NKV + hk) * HD + dc * 8;
      bf16x8 v8 = *(const bf16x8*)src;
#pragma unroll
      for (int j = 0; j < 8; j++) Vt[(dc * 8 + j) * VT_STRIDE + kk] = ((unsigned short*)&v8)[j];
    }
    __syncthreads();
    f32x4 sfr[4];
#pragma unroll
    for (int kt = 0; kt < 4; kt++) {
      f32x4 acc = {0.f, 0.f, 0.f, 0.f};
      const unsigned short* kp = &Ks[(kt * 16 + l16) * KS_STRIDE + quad * 8];
#pragma unroll
      for (int s = 0; s < 4; s++)
        acc = __builtin_amdgcn_mfma_f32_16x16x32_bf16(qf[s], *(const bf16x8*)(kp + s * 32),
                                                      acc, 0, 0, 0);
      sfr[kt] = acc;
    }
    if (t < nt - 1) {
#pragma unroll
      for (int kt = 0; kt < 4; kt++)
#pragma unroll
        for (int r = 0; r < 4; r++) {
          float e = expf(fminf(sfr[kt][r] * sscale, 80.0f));
          float p = fminf(rintf(e * il[r]), 127.0f);
          Ps[(wave * 16 + quad * 4 + r) * PS_STRIDE + kt * 16 + l16] = f2bf(p);
        }
    } else {
#pragma unroll
      for (int kt = 0; kt < 4; kt++) {
        const int key = j0 + kt * 16 + l16;
#pragma unroll
        for (int r = 0; r < 4; r++) {
          float e = expf(fminf(sfr[kt][r] * sscale, 80.0f));
          float p = (key <= qrow_base + r) ? fminf(rintf(e * il[r]), 127.0f) : 0.0f;
          Ps[(wave * 16 + quad * 4 + r) * PS_STRIDE + kt * 16 + l16] = f2bf(p);
        }
      }
    }
    __syncthreads();  // Ps C-layout writes -> A-layout reads (cross-lane)
    bf16x8 pf[2];
    {
      const unsigned short* pp = &Ps[(wave * 16 + l16) * PS_STRIDE + quad * 8];
      pf[0] = *(const bf16x8*)pp;
      pf[1] = *(const bf16x8*)(pp + 32);
    }
#pragma unroll
    for (int n = 0; n < 8; n++) {
      const unsigned short* vp = &Vt[(n * 16 + l16) * VT_STRIDE + quad * 8];
      of[n] = __builtin_amdgcn_mfma_f32_16x16x32_bf16(pf[0], *(const bf16x8*)vp, of[n], 0, 0, 0);
      of[n] = __builtin_amdgcn_mfma_f32_16x16x32_bf16(pf[1], *(const bf16x8*)(vp + 32), of[n],
                                                      0, 0, 0);
    }
  }

  // ---- epilogue: scale, store, fused absmax ----
  const float oscale = scale_p * s_v;
  float amax = 0.0f;
#pragma unroll
  for (int n = 0; n < 8; n++)
#pragma unroll
    for (int r = 0; r < 4; r++) {
      float v = of[n][r] * oscale;
      ob[((size_t)(b * SEQ + qrow_base + r) * NH + h) * HD + n * 16 + l16] = v;
      amax = fmaxf(amax, fabsf(v));
    }
  __syncthreads();
  block_amax_atomic(amax, &slots[8]);
}

extern "C" void kernel_launch(void* const* d_in, const int* in_sizes, int n_in,
                              void* d_out, int out_size, void* d_ws, size_t ws_size,
                              hipStream_t stream) {
  const float* hs = (const float*)d_in[0];
  const float* wq = (const float*)d_in[3];
  const float* wk = (const float*)d_in[4];
  const float* wv = (const float*)d_in[5];
  const float* wo = (const float*)d_in[6];
  float* out = (float*)d_out;

  unsigned int* slots = (unsigned int*)d_ws;
  char* p = (char*)d_ws + 256;
  unsigned short* hsq = (unsigned short*)p;  p += 2 * N_HS;  // dead after proj GEMMs
  unsigned short* wqq = (unsigned short*)p;  p += 2 * N_WQ;
  unsigned short* wkq = (unsigned short*)p;  p += 2 * N_WKV;
  unsigned short* wvq = (unsigned short*)p;  p += 2 * N_WKV;
  unsigned short* woq = (unsigned short*)p;  p += 2 * N_WO;
  float* kbuf = (float*)p;                   p += 4 * N_KV;
  float* vbuf = (float*)p;                   p += 4 * N_KV;
  unsigned short* qbf = (unsigned short*)p;  p += 2 * N_Q;
  unsigned short* kbf = (unsigned short*)p;  p += 2 * N_KV;
  unsigned short* vbf = (unsigned short*)p;
  unsigned short* aobf = hsq;  // alias: hsq dead after V-proj GEMM
  float* qbuf = out;           // fp32 q-proj output lives in d_out
  float* aobuf = out;          // fp32 attn output lives in d_out

  hipMemsetAsync(d_ws, 0, 256, stream);

  // slots: 0=x 1=wq 2=wk 3=wv 4=wo 5=q 6=k 7=v 8=ao
  absmax5_k<<<dim3(128, 5), 256, 0, stream>>>(hs, wq, wk, wv, wo, slots);
  quant5_k<<<dim3(128, 5), 256, 0, stream>>>(hs, wq, wk, wv, wo, slots, hsq, wqq, wkq, wvq, woq);

  const int M = BATCH * SEQ;
  gemm_bt_mfma<<<dim3((NH * HD) / 128, M / 128), 256, 0, stream>>>(hsq, wqq, qbuf, M, NH * HD,
                                                                   HID, slots, 0, 1);
  gemm_bt_mfma<<<dim3((NKV * HD) / 128, M / 128), 256, 0, stream>>>(hsq, wkq, kbuf, M, NKV * HD,
                                                                    HID, slots, 0, 2);
  gemm_bt_mfma<<<dim3((NKV * HD) / 128, M / 128), 256, 0, stream>>>(hsq, wvq, vbuf, M, NKV * HD,
                                                                    HID, slots, 0, 3);

  rope_kernel<<<(BATCH * SEQ * NH * (HD / 2)) / 256, 256, 0, stream>>>(qbuf, NH, slots + 5);
  rope_kernel<<<(BATCH * SEQ * NKV * (HD / 2)) / 256, 256, 0, stream>>>(kbuf, NKV, slots + 6);
  absmax1_k<<<128, 256, 0, stream>>>(vbuf, N_KV / 4, slots + 7);

  quant3_k<<<dim3(128, 3), 256, 0, stream>>>(qbuf, kbuf, vbuf, slots, qbf, kbf, vbf);

  attn_mfma_kernel<<<dim3(SEQ / 64, NH, BATCH), 256, 0, stream>>>(qbf, kbf, vbf, aobuf, slots);

  quant1_k<<<256, 256, 0, stream>>>(aobuf, N_Q / 4, slots + 8, aobf);

  gemm_bt_mfma<<<dim3(HID / 128, M / 128), 256, 0, stream>>>(aobf, woq, out, M, HID, NH * HD,
                                                             slots, 8, 4);
}

// Round 8
// 906.935 us; speedup vs baseline: 8.7466x; 1.0058x over previous
//
#include <hip/hip_runtime.h>
#include <math.h>
#include <stdint.h>
#include <stddef.h>

#define HID 2048
#define NH 16
#define NKV 4
#define HD 128
#define GROUPS (NH / NKV)
#define BATCH 2
#define SEQ 2048

#define N_HS  8388608ull
#define N_Q   8388608ull
#define N_KV  2097152ull
#define N_WQ  4194304ull
#define N_WKV 1048576ull
#define N_WO  4194304ull

typedef __attribute__((ext_vector_type(8))) short bf16x8;
typedef __attribute__((ext_vector_type(4))) float f32x4;

__device__ inline float quantv(float x, float s) {
  float q = rintf(x / s);
  return fminf(fmaxf(q, -128.0f), 127.0f);
}

__device__ inline float slot_scale(const unsigned int* slots, int i) {
  return fmaxf(__uint_as_float(slots[i]) / 127.0f, 1e-8f);
}

__device__ inline unsigned short f2bf(float x) {
  return (unsigned short)(__float_as_uint(x) >> 16);
}

__device__ inline float amax4(float4 v) {
  return fmaxf(fmaxf(fabsf(v.x), fabsf(v.y)), fmaxf(fabsf(v.z), fabsf(v.w)));
}

__device__ inline void block_amax_atomic(float m, unsigned int* slot) {
  __shared__ float red[256];
  red[threadIdx.x] = m;
  __syncthreads();
  for (int o = 128; o > 0; o >>= 1) {
    if (threadIdx.x < o) red[threadIdx.x] = fmaxf(red[threadIdx.x], red[threadIdx.x + o]);
    __syncthreads();
  }
  if (threadIdx.x == 0) atomicMax(slot, __float_as_uint(red[0]));
}

// ---------------- fused absmax over the 5 input tensors ----------------
__global__ __launch_bounds__(256) void absmax5_k(const float* __restrict__ a0,
                                                 const float* __restrict__ a1,
                                                 const float* __restrict__ a2,
                                                 const float* __restrict__ a3,
                                                 const float* __restrict__ a4,
                                                 unsigned int* __restrict__ slots) {
  const int t = blockIdx.y;
  const float* x = t == 0 ? a0 : t == 1 ? a1 : t == 2 ? a2 : t == 3 ? a3 : a4;
  const size_t n4 = (t == 0 ? N_HS : t == 1 ? N_WQ : t == 2 ? N_WKV : t == 3 ? N_WKV : N_WO) / 4;
  const float4* xp = (const float4*)x;
  float m = 0.0f;
  for (size_t i = (size_t)blockIdx.x * 256 + threadIdx.x; i < n4; i += (size_t)gridDim.x * 256)
    m = fmaxf(m, amax4(xp[i]));
  block_amax_atomic(m, slots + t);
}

// ---------------- fused quantize over 5 tensors ----------------
__global__ __launch_bounds__(256) void quant5_k(const float* __restrict__ a0,
                                                const float* __restrict__ a1,
                                                const float* __restrict__ a2,
                                                const float* __restrict__ a3,
                                                const float* __restrict__ a4,
                                                const unsigned int* __restrict__ slots,
                                                unsigned short* __restrict__ o0,
                                                unsigned short* __restrict__ o1,
                                                unsigned short* __restrict__ o2,
                                                unsigned short* __restrict__ o3,
                                                unsigned short* __restrict__ o4) {
  const int t = blockIdx.y;
  const float* x = t == 0 ? a0 : t == 1 ? a1 : t == 2 ? a2 : t == 3 ? a3 : a4;
  unsigned short* o = t == 0 ? o0 : t == 1 ? o1 : t == 2 ? o2 : t == 3 ? o3 : o4;
  const size_t n4 = (t == 0 ? N_HS : t == 1 ? N_WQ : t == 2 ? N_WKV : t == 3 ? N_WKV : N_WO) / 4;
  const float s = fmaxf(__uint_as_float(slots[t]) / 127.0f, 1e-8f);
  const float4* xp = (const float4*)x;
  ushort4* op = (ushort4*)o;
  for (size_t i = (size_t)blockIdx.x * 256 + threadIdx.x; i < n4; i += (size_t)gridDim.x * 256) {
    float4 v = xp[i];
    ushort4 r;
    r.x = f2bf(quantv(v.x, s));
    r.y = f2bf(quantv(v.y, s));
    r.z = f2bf(quantv(v.z, s));
    r.w = f2bf(quantv(v.w, s));
    op[i] = r;
  }
}

// ---------------- fused quantize q/k ----------------
__global__ __launch_bounds__(256) void quant2_k(const float* __restrict__ a0,
                                                const float* __restrict__ a1,
                                                const unsigned int* __restrict__ slots,
                                                unsigned short* __restrict__ o0,
                                                unsigned short* __restrict__ o1) {
  const int t = blockIdx.y;
  const float* x = t == 0 ? a0 : a1;
  unsigned short* o = t == 0 ? o0 : o1;
  const size_t n4 = (t == 0 ? N_Q : N_KV) / 4;
  const float s = fmaxf(__uint_as_float(slots[5 + t]) / 127.0f, 1e-8f);
  const float4* xp = (const float4*)x;
  ushort4* op = (ushort4*)o;
  for (size_t i = (size_t)blockIdx.x * 256 + threadIdx.x; i < n4; i += (size_t)gridDim.x * 256) {
    float4 v = xp[i];
    ushort4 r;
    r.x = f2bf(quantv(v.x, s));
    r.y = f2bf(quantv(v.y, s));
    r.z = f2bf(quantv(v.z, s));
    r.w = f2bf(quantv(v.w, s));
    op[i] = r;
  }
}

__global__ __launch_bounds__(256) void quant1_k(const float* __restrict__ x, size_t n4,
                                                const unsigned int* __restrict__ slot,
                                                unsigned short* __restrict__ out) {
  const float s = fmaxf(__uint_as_float(*slot) / 127.0f, 1e-8f);
  const float4* xp = (const float4*)x;
  ushort4* op = (ushort4*)out;
  for (size_t i = (size_t)blockIdx.x * 256 + threadIdx.x; i < n4; i += (size_t)gridDim.x * 256) {
    float4 v = xp[i];
    ushort4 r;
    r.x = f2bf(quantv(v.x, s));
    r.y = f2bf(quantv(v.y, s));
    r.z = f2bf(quantv(v.z, s));
    r.w = f2bf(quantv(v.w, s));
    op[i] = r;
  }
}

// ---------------- V: quantize + transpose to [b][hk][d][s] ----------------
__global__ __launch_bounds__(256) void vtq_k(const float* __restrict__ vbuf,
                                             const unsigned int* __restrict__ slots,
                                             unsigned short* __restrict__ vbt) {
  __shared__ unsigned short L[128 * 72];
  const int tid = threadIdx.x;
  const int s0 = blockIdx.x * 64;
  const int hk = blockIdx.y;
  const int b = blockIdx.z;
  const float s = fmaxf(__uint_as_float(slots[7]) / 127.0f, 1e-8f);
#pragma unroll
  for (int it = 0; it < 8; it++) {
    int idx = tid + it * 256;
    int sl = idx >> 5, c4 = idx & 31;
    float4 v = ((const float4*)(vbuf + ((size_t)(b * SEQ + s0 + sl) * NKV + hk) * HD))[c4];
    L[(c4 * 4 + 0) * 72 + sl] = f2bf(quantv(v.x, s));
    L[(c4 * 4 + 1) * 72 + sl] = f2bf(quantv(v.y, s));
    L[(c4 * 4 + 2) * 72 + sl] = f2bf(quantv(v.z, s));
    L[(c4 * 4 + 3) * 72 + sl] = f2bf(quantv(v.w, s));
  }
  __syncthreads();
  const size_t obase = ((size_t)(b * NKV + hk)) * HD * SEQ + s0;
#pragma unroll
  for (int it = 0; it < 4; it++) {
    int idx = tid + it * 256;
    int d = idx >> 3, sc = idx & 7;
    *(bf16x8*)(vbt + obase + (size_t)d * SEQ + sc * 8) = *(const bf16x8*)(&L[d * 72 + sc * 8]);
  }
}

// ---------------- MFMA GEMM with register prefetch + optional fused absmax -------------
__global__ __launch_bounds__(256) void gemm_bt_mfma(const unsigned short* __restrict__ A,
                                                    const unsigned short* __restrict__ B,
                                                    float* __restrict__ C, int M, int N, int K,
                                                    unsigned int* __restrict__ slots,
                                                    int ia, int ib, int amax_slot) {
  __shared__ unsigned short As[128 * 32];
  __shared__ unsigned short Bs[128 * 32];
  const int tid = threadIdx.x;
  const int wave = tid >> 6, lane = tid & 63;
  const int l16 = lane & 15, quad = lane >> 4;
  const int n0 = blockIdx.x * 128, m0 = blockIdx.y * 128;
  const int wm = (wave & 1) * 64, wn = (wave >> 1) * 64;
  const float sc = slot_scale(slots, ia) * slot_scale(slots, ib);

  f32x4 acc[4][4];
#pragma unroll
  for (int i = 0; i < 4; i++)
#pragma unroll
    for (int j = 0; j < 4; j++) acc[i][j] = (f32x4){0.f, 0.f, 0.f, 0.f};

  bf16x8 ar[2], br[2];
#pragma unroll
  for (int it = 0; it < 2; it++) {
    int c = it * 256 + tid;
    int row = c >> 2, kc = (c & 3) * 8;
    ar[it] = *(const bf16x8*)(A + (size_t)(m0 + row) * K + kc);
    br[it] = *(const bf16x8*)(B + (size_t)(n0 + row) * K + kc);
  }
  for (int kt = 0; kt < K; kt += 32) {
    __syncthreads();
#pragma unroll
    for (int it = 0; it < 2; it++) {
      int c = it * 256 + tid;
      int row = c >> 2, kc = (c & 3) * 8;
      *(bf16x8*)(&As[row * 32 + kc]) = ar[it];
      *(bf16x8*)(&Bs[row * 32 + kc]) = br[it];
    }
    if (kt + 32 < K) {
#pragma unroll
      for (int it = 0; it < 2; it++) {
        int c = it * 256 + tid;
        int row = c >> 2, kc = (c & 3) * 8;
        ar[it] = *(const bf16x8*)(A + (size_t)(m0 + row) * K + kt + 32 + kc);
        br[it] = *(const bf16x8*)(B + (size_t)(n0 + row) * K + kt + 32 + kc);
      }
    }
    __syncthreads();
    bf16x8 af[4], bf[4];
#pragma unroll
    for (int i = 0; i < 4; i++)
      af[i] = *(const bf16x8*)(&As[(wm + i * 16 + l16) * 32 + quad * 8]);
#pragma unroll
    for (int j = 0; j < 4; j++)
      bf[j] = *(const bf16x8*)(&Bs[(wn + j * 16 + l16) * 32 + quad * 8]);
#pragma unroll
    for (int i = 0; i < 4; i++)
#pragma unroll
      for (int j = 0; j < 4; j++)
        acc[i][j] = __builtin_amdgcn_mfma_f32_16x16x32_bf16(af[i], bf[j], acc[i][j], 0, 0, 0);
  }

  float am = 0.0f;
#pragma unroll
  for (int i = 0; i < 4; i++)
#pragma unroll
    for (int j = 0; j < 4; j++)
#pragma unroll
      for (int r = 0; r < 4; r++) {
        int row = m0 + wm + i * 16 + quad * 4 + r;
        int col = n0 + wn + j * 16 + l16;
        float v = acc[i][j][r] * sc;
        C[(size_t)row * N + col] = v;
        am = fmaxf(am, fabsf(v));
      }
  if (amax_slot >= 0) {
    __syncthreads();
    float* red = (float*)As;
    red[tid] = am;
    __syncthreads();
    for (int o = 128; o > 0; o >>= 1) {
      if (tid < o) red[tid] = fmaxf(red[tid], red[tid + o]);
      __syncthreads();
    }
    if (tid == 0) atomicMax(slots + amax_slot, __float_as_uint(red[0]));
  }
}

// ---------------- RoPE in-place + absmax ----------------
__global__ __launch_bounds__(256) void rope_kernel(float* __restrict__ t, int nh,
                                                   unsigned int* __restrict__ slot) {
  size_t idx = (size_t)blockIdx.x * 256 + threadIdx.x;
  size_t total = (size_t)BATCH * SEQ * nh * (HD / 2);
  float am = 0.0f;
  if (idx < total) {
    int i = (int)(idx & 63);
    int h = (int)((idx >> 6) % nh);
    int s = (int)((idx / (64ull * nh)) % SEQ);
    int b = (int)(idx / (64ull * nh * SEQ));
    size_t base = ((size_t)(b * SEQ + s) * nh + h) * HD;
    float inv = 1.0f / powf(10000.0f, (float)(2 * i) * (1.0f / 128.0f));
    float fr = (float)s * inv;
    float c = cosf(fr), sn = sinf(fr);
    float x1 = t[base + i], x2 = t[base + i + 64];
    float r1 = x1 * c - x2 * sn;
    float r2 = x2 * c + x1 * sn;
    t[base + i] = r1;
    t[base + i + 64] = r2;
    am = fmaxf(fabsf(r1), fabsf(r2));
  }
  block_amax_atomic(am, slot);
}

// ---------------- MFMA paired-tile two-pass causal attention ----------------
#define TK 64
#define KS_STRIDE (HD + 8)
#define VT_STRIDE (TK + 8)
#define PS_STRIDE (TK + 8)

__device__ __forceinline__ void ldK(bf16x8 r[4], const unsigned short* kb, int b, int hk,
                                    int j0, int tid) {
#pragma unroll
  for (int it = 0; it < 4; it++) {
    int c2 = tid + it * 256;
    int rr = c2 >> 4, c = c2 & 15;
    r[it] = *(const bf16x8*)(kb + ((size_t)(b * SEQ + j0 + rr) * NKV + hk) * HD + c * 8);
  }
}
__device__ __forceinline__ void stK(unsigned short* Ks, const bf16x8 r[4], int tid) {
#pragma unroll
  for (int it = 0; it < 4; it++) {
    int c2 = tid + it * 256;
    int rr = c2 >> 4, c = c2 & 15;
    *(bf16x8*)(&Ks[rr * KS_STRIDE + c * 8]) = r[it];
  }
}
__device__ __forceinline__ void ldV(bf16x8 r[4], const unsigned short* vbt, size_t vbase,
                                    int j0, int tid) {
#pragma unroll
  for (int it = 0; it < 4; it++) {
    int idx = tid + it * 256;
    int d = idx >> 3, sc = idx & 7;
    r[it] = *(const bf16x8*)(vbt + vbase + (size_t)d * SEQ + j0 + sc * 8);
  }
}
__device__ __forceinline__ void stV(unsigned short* Vt, const bf16x8 r[4], int tid) {
#pragma unroll
  for (int it = 0; it < 4; it++) {
    int idx = tid + it * 256;
    int d = idx >> 3, sc = idx & 7;
    *(bf16x8*)(&Vt[d * VT_STRIDE + sc * 8]) = r[it];
  }
}
__device__ __forceinline__ void qk4(f32x4 sfr[4], const unsigned short* Ks, const bf16x8 qf[4],
                                    int l16, int quad) {
#pragma unroll
  for (int kt = 0; kt < 4; kt++) {
    f32x4 acc = {0.f, 0.f, 0.f, 0.f};
    const unsigned short* kp = &Ks[(kt * 16 + l16) * KS_STRIDE + quad * 8];
#pragma unroll
    for (int s = 0; s < 4; s++)
      acc = __builtin_amdgcn_mfma_f32_16x16x32_bf16(qf[s], *(const bf16x8*)(kp + s * 32), acc,
                                                    0, 0, 0);
    sfr[kt] = acc;
  }
}
__device__ __forceinline__ void lacc(float l[4], const f32x4 sfr[4], float ss, bool diag,
                                     int j0, int qrb, int l16) {
  if (!diag) {
#pragma unroll
    for (int kt = 0; kt < 4; kt++)
#pragma unroll
      for (int r = 0; r < 4; r++) l[r] += expf(fminf(sfr[kt][r] * ss, 80.0f));
  } else {
#pragma unroll
    for (int kt = 0; kt < 4; kt++) {
      const int key = j0 + kt * 16 + l16;
#pragma unroll
      for (int r = 0; r < 4; r++) {
        float e = expf(fminf(sfr[kt][r] * ss, 80.0f));
        l[r] += (key <= qrb + r) ? e : 0.0f;
      }
    }
  }
}
__device__ __forceinline__ void pquant(unsigned short* Ps, const f32x4 sfr[4],
                                       const float il[4], float ss, bool diag, int j0,
                                       int qrb, int wave, int l16, int quad) {
  if (!diag) {
#pragma unroll
    for (int kt = 0; kt < 4; kt++)
#pragma unroll
      for (int r = 0; r < 4; r++) {
        float e = expf(fminf(sfr[kt][r] * ss, 80.0f));
        float p = fminf(rintf(e * il[r]), 127.0f);
        Ps[(wave * 16 + quad * 4 + r) * PS_STRIDE + kt * 16 + l16] = f2bf(p);
      }
  } else {
#pragma unroll
    for (int kt = 0; kt < 4; kt++) {
      const int key = j0 + kt * 16 + l16;
#pragma unroll
      for (int r = 0; r < 4; r++) {
        float e = expf(fminf(sfr[kt][r] * ss, 80.0f));
        float p = (key <= qrb + r) ? fminf(rintf(e * il[r]), 127.0f) : 0.0f;
        Ps[(wave * 16 + quad * 4 + r) * PS_STRIDE + kt * 16 + l16] = f2bf(p);
      }
    }
  }
}
__device__ __forceinline__ void pvacc(f32x4 of[8], const unsigned short* Ps,
                                      const unsigned short* Vt, int wave, int l16, int quad) {
  const unsigned short* pp = &Ps[(wave * 16 + l16) * PS_STRIDE + quad * 8];
  bf16x8 pf0 = *(const bf16x8*)pp;
  bf16x8 pf1 = *(const bf16x8*)(pp + 32);
#pragma unroll
  for (int n = 0; n < 8; n++) {
    const unsigned short* vp = &Vt[(n * 16 + l16) * VT_STRIDE + quad * 8];
    of[n] = __builtin_amdgcn_mfma_f32_16x16x32_bf16(pf0, *(const bf16x8*)vp, of[n], 0, 0, 0);
    of[n] = __builtin_amdgcn_mfma_f32_16x16x32_bf16(pf1, *(const bf16x8*)(vp + 32), of[n],
                                                    0, 0, 0);
  }
}

__global__ __launch_bounds__(256, 2) void attn_mfma_kernel(const unsigned short* __restrict__ qb,
                                                           const unsigned short* __restrict__ kb,
                                                           const unsigned short* __restrict__ vbt,
                                                           float* __restrict__ ob,
                                                           unsigned int* __restrict__ slots) {
  __shared__ unsigned short Ks[TK * KS_STRIDE];
  __shared__ unsigned short Vt[HD * VT_STRIDE];
  __shared__ unsigned short Ps[64 * PS_STRIDE];

  const int tid = threadIdx.x;
  const int wave = tid >> 6;
  const int lane = tid & 63;
  const int l16 = lane & 15;
  const int quad = lane >> 4;
  const int slot = blockIdx.x;  // 0..15: q-tiles slot and 31-slot (equal total work)
  const int h = blockIdx.y;
  const int b = blockIdx.z;
  const int hk = h / GROUPS;
  const int q0A = slot * 64, ntA = slot + 1;
  const int q0B = (31 - slot) * 64, ntB = 32 - slot;

  const float s_q = slot_scale(slots, 5);
  const float s_k = slot_scale(slots, 6);
  const float s_v = slot_scale(slots, 7);
  const float ss = s_q * s_k / 11.313708498984761f;  // /sqrt(128)
  const float scale_p = 1.0f / 127.0f;
  const size_t vbase = ((size_t)(b * NKV + hk)) * HD * SEQ;

  bf16x8 qfA[4], qfB[4];
  {
    const unsigned short* qpA =
        qb + ((size_t)(b * SEQ + q0A + wave * 16 + l16) * NH + h) * HD + quad * 8;
    const unsigned short* qpB =
        qb + ((size_t)(b * SEQ + q0B + wave * 16 + l16) * NH + h) * HD + quad * 8;
#pragma unroll
    for (int s = 0; s < 4; s++) {
      qfA[s] = *(const bf16x8*)(qpA + s * 32);
      qfB[s] = *(const bf16x8*)(qpB + s * 32);
    }
  }
  const int qrbA = q0A + wave * 16 + quad * 4;
  const int qrbB = q0B + wave * 16 + quad * 4;

  // ---- Pass A: l sums for both q-tiles ----
  float lA[4] = {0.f, 0.f, 0.f, 0.f}, lB[4] = {0.f, 0.f, 0.f, 0.f};
  bf16x8 kreg[4];
  ldK(kreg, kb, b, hk, 0, tid);
  for (int t = 0; t < ntB; t++) {
    const int j0 = t * TK;
    __syncthreads();
    stK(Ks, kreg, tid);
    if (t + 1 < ntB) ldK(kreg, kb, b, hk, (t + 1) * TK, tid);
    __syncthreads();
    f32x4 sfr[4];
    if (t < ntA) {
      qk4(sfr, Ks, qfA, l16, quad);
      lacc(lA, sfr, ss, t == ntA - 1, j0, qrbA, l16);
    }
    qk4(sfr, Ks, qfB, l16, quad);
    lacc(lB, sfr, ss, t == ntB - 1, j0, qrbB, l16);
  }
  float ilA[4], ilB[4];
#pragma unroll
  for (int r = 0; r < 4; r++) {
#pragma unroll
    for (int off = 1; off < 16; off <<= 1) {
      lA[r] += __shfl_xor(lA[r], off);
      lB[r] += __shfl_xor(lB[r], off);
    }
    ilA[r] = 127.0f / fmaxf(lA[r], 1e-30f);
    ilB[r] = 127.0f / fmaxf(lB[r], 1e-30f);
  }

  // ---- Pass B: recompute S, quantize P, PV for both q-tiles ----
  f32x4 ofA[8], ofB[8];
#pragma unroll
  for (int n = 0; n < 8; n++) {
    ofA[n] = (f32x4){0.f, 0.f, 0.f, 0.f};
    ofB[n] = (f32x4){0.f, 0.f, 0.f, 0.f};
  }
  bf16x8 vreg[4];
  ldK(kreg, kb, b, hk, 0, tid);
  ldV(vreg, vbt, vbase, 0, tid);
  for (int t = 0; t < ntB; t++) {
    const int j0 = t * TK;
    __syncthreads();
    stK(Ks, kreg, tid);
    stV(Vt, vreg, tid);
    if (t + 1 < ntB) {
      ldK(kreg, kb, b, hk, (t + 1) * TK, tid);
      ldV(vreg, vbt, vbase, (t + 1) * TK, tid);
    }
    __syncthreads();
    f32x4 sfr[4];
    if (t < ntA) {
      qk4(sfr, Ks, qfA, l16, quad);
      pquant(Ps, sfr, ilA, ss, t == ntA - 1, j0, qrbA, wave, l16, quad);
      pvacc(ofA, Ps, Vt, wave, l16, quad);  // Ps rows are wave-private; in-wave LDS order
    }
    qk4(sfr, Ks, qfB, l16, quad);
    pquant(Ps, sfr, ilB, ss, t == ntB - 1, j0, qrbB, wave, l16, quad);
    pvacc(ofB, Ps, Vt, wave, l16, quad);
  }

  // ---- epilogue ----
  const float oscale = scale_p * s_v;
  float amax = 0.0f;
#pragma unroll
  for (int n = 0; n < 8; n++)
#pragma unroll
    for (int r = 0; r < 4; r++) {
      float vA = ofA[n][r] * oscale;
      float vB = ofB[n][r] * oscale;
      ob[((size_t)(b * SEQ + qrbA + r) * NH + h) * HD + n * 16 + l16] = vA;
      ob[((size_t)(b * SEQ + qrbB + r) * NH + h) * HD + n * 16 + l16] = vB;
      amax = fmaxf(amax, fmaxf(fabsf(vA), fabsf(vB)));
    }
  __syncthreads();
  block_amax_atomic(amax, &slots[8]);
}

extern "C" void kernel_launch(void* const* d_in, const int* in_sizes, int n_in,
                              void* d_out, int out_size, void* d_ws, size_t ws_size,
                              hipStream_t stream) {
  const float* hs = (const float*)d_in[0];
  const float* wq = (const float*)d_in[3];
  const float* wk = (const float*)d_in[4];
  const float* wv = (const float*)d_in[5];
  const float* wo = (const float*)d_in[6];
  float* out = (float*)d_out;

  unsigned int* slots = (unsigned int*)d_ws;
  char* p = (char*)d_ws + 256;
  unsigned short* hsq = (unsigned short*)p;  p += 2 * N_HS;  // dead after proj GEMMs
  unsigned short* wqq = (unsigned short*)p;  p += 2 * N_WQ;
  unsigned short* wkq = (unsigned short*)p;  p += 2 * N_WKV;
  unsigned short* wvq = (unsigned short*)p;  p += 2 * N_WKV;
  unsigned short* woq = (unsigned short*)p;  p += 2 * N_WO;
  float* kbuf = (float*)p;                   p += 4 * N_KV;
  float* vbuf = (float*)p;                   p += 4 * N_KV;
  unsigned short* qbf = (unsigned short*)p;  p += 2 * N_Q;
  unsigned short* kbf = (unsigned short*)p;  p += 2 * N_KV;
  unsigned short* vbt = (unsigned short*)p;  // transposed quantized V
  unsigned short* aobf = hsq;  // alias: hsq dead after V-proj GEMM
  float* qbuf = out;           // fp32 q-proj output lives in d_out
  float* aobuf = out;          // fp32 attn output lives in d_out

  hipMemsetAsync(d_ws, 0, 256, stream);

  // slots: 0=x 1=wq 2=wk 3=wv 4=wo 5=q 6=k 7=v 8=ao
  absmax5_k<<<dim3(128, 5), 256, 0, stream>>>(hs, wq, wk, wv, wo, slots);
  quant5_k<<<dim3(128, 5), 256, 0, stream>>>(hs, wq, wk, wv, wo, slots, hsq, wqq, wkq, wvq, woq);

  const int M = BATCH * SEQ;
  gemm_bt_mfma<<<dim3((NH * HD) / 128, M / 128), 256, 0, stream>>>(hsq, wqq, qbuf, M, NH * HD,
                                                                   HID, slots, 0, 1, -1);
  gemm_bt_mfma<<<dim3((NKV * HD) / 128, M / 128), 256, 0, stream>>>(hsq, wkq, kbuf, M, NKV * HD,
                                                                    HID, slots, 0, 2, -1);
  gemm_bt_mfma<<<dim3((NKV * HD) / 128, M / 128), 256, 0, stream>>>(hsq, wvq, vbuf, M, NKV * HD,
                                                                    HID, slots, 0, 3, 7);

  rope_kernel<<<(BATCH * SEQ * NH * (HD / 2)) / 256, 256, 0, stream>>>(qbuf, NH, slots + 5);
  rope_kernel<<<(BATCH * SEQ * NKV * (HD / 2)) / 256, 256, 0, stream>>>(kbuf, NKV, slots + 6);

  quant2_k<<<dim3(128, 2), 256, 0, stream>>>(qbuf, kbuf, slots, qbf, kbf);
  vtq_k<<<dim3(SEQ / 64, NKV, BATCH), 256, 0, stream>>>(vbuf, slots, vbt);

  attn_mfma_kernel<<<dim3(16, NH, BATCH), 256, 0, stream>>>(qbf, kbf, vbt, aobuf, slots);

  quant1_k<<<256, 256, 0, stream>>>(aobuf, N_Q / 4, slots + 8, aobf);

  gemm_bt_mfma<<<dim3(HID / 128, M / 128), 256, 0, stream>>>(aobf, woq, out, M, HID, NH * HD,
                                                             slots, 8, 4, -1);
}